// Round 11
// baseline (169.675 us; speedup 1.0000x reference)
//
#include <hip/hip_runtime.h>
#include <hip/hip_bf16.h>
#include <stdint.h>

typedef unsigned short u16;
typedef __attribute__((ext_vector_type(8))) unsigned short u16x8;
typedef __attribute__((ext_vector_type(4))) unsigned short u16x4;
typedef __attribute__((ext_vector_type(8))) __bf16 bf16x8;
typedef __attribute__((ext_vector_type(4))) float f32x4;
typedef __attribute__((ext_vector_type(16))) float f32x16;

#define LOG2E 1.44269504088896340736f

#if defined(__has_builtin)
#if __has_builtin(__builtin_amdgcn_exp2f)
#define EXP2(x) __builtin_amdgcn_exp2f(x)
#endif
#endif
#ifndef EXP2
#define EXP2(x) exp2f(x)
#endif

// ---------- helpers ----------
__device__ __forceinline__ f32x4 mfma16(u16x8 a, u16x8 b, f32x4 c) {
  return __builtin_amdgcn_mfma_f32_16x16x32_bf16(
      __builtin_bit_cast(bf16x8, a), __builtin_bit_cast(bf16x8, b), c, 0, 0, 0);
}

__device__ __forceinline__ f32x16 mfma32(u16x8 a, u16x8 b, f32x16 c) {
  return __builtin_amdgcn_mfma_f32_32x32x16_bf16(
      __builtin_bit_cast(bf16x8, a), __builtin_bit_cast(bf16x8, b), c, 0, 0, 0);
}

__device__ __forceinline__ u16 f2bf(float f) {
  unsigned u = __builtin_bit_cast(unsigned, f);
  return (u16)((u + 0x7fffu + ((u >> 16) & 1u)) >> 16);
}

__device__ __forceinline__ unsigned cvtpk(float a, float b) {
  unsigned r;
  asm volatile("v_cvt_pk_bf16_f32 %0, %1, %2" : "=v"(r) : "v"(a), "v"(b));
  return r;
}

// v_permlane32_swap_b32: a[32..63] <-> b[0..31]
__device__ __forceinline__ void pswap(unsigned& a, unsigned& b) {
  asm volatile("v_permlane32_swap_b32 %0, %1" : "+v"(a), "+v"(b));
}

__device__ __forceinline__ void gload_lds16(const void* g, void* l) {
  __builtin_amdgcn_global_load_lds(
      (__attribute__((address_space(1))) void*)const_cast<void*>(g),
      (__attribute__((address_space(3))) void*)l, 16, 0, 0);
}

template<int N> __device__ __forceinline__ void vmwait() {
  __builtin_amdgcn_sched_barrier(0);
  asm volatile("s_waitcnt vmcnt(%0)" :: "n"(N) : "memory");
  __builtin_amdgcn_sched_barrier(0);
}

#define SWZ(row, colbyte) ((((row) * 128) + (colbyte)) ^ (((row) & 7) << 4))

// ---------- fp32 -> bf16 casts ----------
__global__ void cast_f32_bf16(const float* __restrict__ src, u16* __restrict__ dst, int n4) {
  int i = blockIdx.x * blockDim.x + threadIdx.x;
  if (i < n4) {
    f32x4 v = ((const f32x4*)src)[i];
    u16x4 o;
    o[0] = f2bf(v[0]); o[1] = f2bf(v[1]); o[2] = f2bf(v[2]); o[3] = f2bf(v[3]);
    ((u16x4*)dst)[i] = o;
  }
}

__global__ void cast3_f32_bf16(const float* __restrict__ s0, const float* __restrict__ s1,
                               const float* __restrict__ s2, u16* __restrict__ dst) {
  const int seg = blockIdx.x >> 10;
  const int i = (blockIdx.x & 1023) * blockDim.x + threadIdx.x;
  const float* src = (seg == 0) ? s0 : ((seg == 1) ? s1 : s2);
  f32x4 v = ((const f32x4*)src)[i];
  u16x4 o;
  o[0] = f2bf(v[0]); o[1] = f2bf(v[1]); o[2] = f2bf(v[2]); o[3] = f2bf(v[3]);
  ((u16x4*)(dst + (size_t)seg * 1048576))[i] = o;
}

// ---------- fused QKV GEMM (3-buf, depth-2 prefetch, counted vmcnt) ----------
__global__ __launch_bounds__(256) void gemm_qkv(
    const u16* __restrict__ A, const u16* __restrict__ Bm,
    const float* __restrict__ bq, const float* __restrict__ bk, const float* __restrict__ bv,
    u16* __restrict__ Qb, u16* __restrict__ Kb, u16* __restrict__ VTb) {
  __shared__ __align__(16) u16 Asm[3][4096];
  __shared__ __align__(16) u16 Bsm[3][4096];
  const int tid = threadIdx.x;
  const int wave = tid >> 6, lane = tid & 63;
  const int lq = lane & 15, lg = lane >> 4;
  const int wr = wave >> 1, wc = wave & 1;
  const int lin = blockIdx.y * 24 + blockIdx.x;
  const int wg = (lin & 7) * 96 + (lin >> 3);
  const int m0 = (wg / 24) * 128, n0 = (wg % 24) * 128;

  f32x4 zero = {0.f, 0.f, 0.f, 0.f};
  f32x4 acc[4][4];
#pragma unroll
  for (int mi = 0; mi < 4; ++mi)
#pragma unroll
    for (int ni = 0; ni < 4; ++ni) acc[mi][ni] = zero;

  auto stage = [&](int kt, int buf) {
    const int k0 = kt * 32;
#pragma unroll
    for (int c = 0; c < 2; ++c) {
      const int idx = wave * 2 + c;
      const u16* ga = A + (size_t)(m0 + idx * 16 + (lane >> 2)) * 1024 + k0 + (lane & 3) * 8;
      gload_lds16(ga, (char*)&Asm[buf][0] + idx * 1024);
      const u16* gb = Bm + (size_t)(n0 + idx * 16 + (lane >> 2)) * 1024 + k0 + (lane & 3) * 8;
      gload_lds16(gb, (char*)&Bsm[buf][0] + idx * 1024);
    }
  };

  stage(0, 0);
  stage(1, 1);
  for (int kt = 0; kt < 32; ++kt) {
    if (kt < 31) vmwait<4>(); else vmwait<0>();
    __builtin_amdgcn_s_barrier();
    if (kt + 2 < 32) stage(kt + 2, (kt + 2) % 3);
    const int cur = kt % 3;

    __builtin_amdgcn_s_setprio(1);
    u16x8 af[4], bfr[4];
#pragma unroll
    for (int mi = 0; mi < 4; ++mi)
      af[mi] = *(const u16x8*)&Asm[cur][(wr * 64 + mi * 16 + lq) * 32 + lg * 8];
#pragma unroll
    for (int ni = 0; ni < 4; ++ni)
      bfr[ni] = *(const u16x8*)&Bsm[cur][(wc * 64 + ni * 16 + lq) * 32 + lg * 8];
#pragma unroll
    for (int mi = 0; mi < 4; ++mi)
#pragma unroll
      for (int ni = 0; ni < 4; ++ni)
        acc[mi][ni] = mfma16(af[mi], bfr[ni], acc[mi][ni]);
    __builtin_amdgcn_s_setprio(0);
  }

  const int which = n0 >> 10;
  const float* bias = (which == 0) ? bq : ((which == 1) ? bk : bv);
  const float scl = (which == 0) ? (0.125f * LOG2E) : 1.0f;
#pragma unroll
  for (int mi = 0; mi < 4; ++mi) {
    const int m = m0 + wr * 64 + mi * 16 + lg * 4;
    const int bb = m >> 11;
    const int s = m & 2047;
#pragma unroll
    for (int ni = 0; ni < 4; ++ni) {
      const int n = n0 + wc * 64 + ni * 16 + lq;
      const int d = n & 1023;
      const int h = d >> 6, dh = d & 63;
      const float bi = bias[d];
#pragma unroll
      for (int r = 0; r < 4; ++r) {
        float v = (acc[mi][ni][r] + bi) * scl;
        if (which == 2)
          VTb[(((size_t)bb * 16 + h) * 64 + dh) * 2048 + (size_t)(s + r)] = f2bf(v);
        else {
          u16* dst = (which == 0) ? Qb : Kb;
          dst[(((size_t)bb * 16 + h) * 2048 + (size_t)(s + r)) * 64 + dh] = f2bf(v);
        }
      }
    }
  }
}

// ---------- attention split-K: partial ctx/l via atomics ----------
// 512 thr = 8 waves, 32 q/wave (q-tile 256); k-half = 1024 (16 tiles).
// Grid 512 = 32 bh x 8 qt x 2 kh -> 2 blocks/CU, 16 waves/CU.
// Unnormalized partial acc atomicAdd'ed into out_ctx; partial l into pl.
__global__ __launch_bounds__(512) void attn_split(
    const u16* __restrict__ Qb, const u16* __restrict__ Kb, const u16* __restrict__ VTb,
    const float* __restrict__ maskg, float* __restrict__ out_ctx, float* __restrict__ pl) {
  __shared__ __align__(16) u16 Kl[3][4096];   // 24 KB
  __shared__ __align__(16) u16 VTl[3][4096];  // 24 KB

  const int tid = threadIdx.x;
  const int w = tid >> 6, lane = tid & 63;
  const int l31 = lane & 31, h = lane >> 5;
  // XCD swizzle: 512 blocks, 64/XCD; consecutive bids share (bh,kh) K/V panel
  const int bid = (blockIdx.x & 7) * 64 + (blockIdx.x >> 3);
  const int qt = bid & 7, kh = (bid >> 3) & 1, bh = bid >> 4;
  const int b = bh >> 4, hh = bh & 15;
  const int qw = qt * 256 + w * 32;  // wave's 32 q rows
  const int kt0 = kh * 16;           // this block's 16 k-tiles

  // Q frags: lane holds Q[qw+l31][dh = 16dq + 8h + j]
  const u16* qp = Qb + ((size_t)bh * 2048 + qw + l31) * 64 + h * 8;
  u16x8 qa[4];
#pragma unroll
  for (int dq = 0; dq < 4; ++dq) qa[dq] = *(const u16x8*)(qp + dq * 16);

  const char* Kbase = (const char*)(Kb + (size_t)bh * 2048 * 64);
  const char* VTbase = (const char*)(VTb + (size_t)bh * 64 * 2048);
  const float* mbase = maskg + b * 2048;

  // staging: 512 x 16B chunks per 8KB tile, 1/thread; pre-swizzled source
  const int srow = tid >> 3;
  const int scol = ((tid & 7) * 16) ^ ((srow & 7) << 4);
  auto stageK = [&](int kt, int buf) {
    gload_lds16(Kbase + (size_t)(kt * 64 + srow) * 128 + scol, (char*)&Kl[buf][0] + w * 1024);
  };
  auto stageVT = [&](int kt, int buf) {
    gload_lds16(VTbase + (size_t)srow * 4096 + (size_t)kt * 128 + scol, (char*)&VTl[buf][0] + w * 1024);
  };

  f32x16 accpv[2];
#pragma unroll
  for (int db = 0; db < 2; ++db)
#pragma unroll
    for (int r = 0; r < 16; ++r) accpv[db][r] = 0.f;
  float l_l = 0.f;

  stageK(kt0, 0); stageVT(kt0, 0);
  stageK(kt0 + 1, 1); stageVT(kt0 + 1, 1);
  for (int j = 0; j < 16; ++j) {
    const int kt = kt0 + j;
    if (j < 15) vmwait<2>(); else vmwait<0>();
    __builtin_amdgcn_s_barrier();
    const char* Kt = (const char*)&Kl[j % 3][0];
    const char* Vt = (const char*)&VTl[j % 3][0];

    __builtin_amdgcn_s_setprio(1);
#pragma unroll
    for (int kb = 0; kb < 2; ++kb) {
      // QK^T: S[k = kt*64 + kb*32 + (r&3)+8(r>>2)+4h][q = l31]
      f32x16 s;
#pragma unroll
      for (int r = 0; r < 16; ++r) s[r] = 0.f;
#pragma unroll
      for (int dq = 0; dq < 4; ++dq) {
        const u16x8 ka = *(const u16x8*)(Kt + SWZ(kb * 32 + l31, dq * 32 + h * 16));
        s = mfma32(ka, qa[dq], s);
      }
      float p[16];
#pragma unroll
      for (int g = 0; g < 4; ++g) {
        const f32x4 mv = *(const f32x4*)(mbase + kt * 64 + kb * 32 + g * 8 + h * 4);
#pragma unroll
        for (int j2 = 0; j2 < 4; ++j2)
          p[g * 4 + j2] = EXP2(fmaf(mv[j2], LOG2E, s[g * 4 + j2]));
      }
      l_l += ((p[0] + p[1]) + (p[2] + p[3])) + ((p[4] + p[5]) + (p[6] + p[7])) +
             ((p[8] + p[9]) + (p[10] + p[11])) + ((p[12] + p[13]) + (p[14] + p[15]));
      // P -> PV A-frags: pairs packed, lane-halves swapped
      unsigned a01 = cvtpk(p[0], p[1]), a23 = cvtpk(p[2], p[3]);
      unsigned a45 = cvtpk(p[4], p[5]), a67 = cvtpk(p[6], p[7]);
      unsigned b01 = cvtpk(p[8], p[9]), b23 = cvtpk(p[10], p[11]);
      unsigned b45 = cvtpk(p[12], p[13]), b67 = cvtpk(p[14], p[15]);
      pswap(a01, a45); pswap(a23, a67);
      pswap(b01, b45); pswap(b23, b67);
      uint4 f1 = {a01, a23, a45, a67};
      uint4 f2 = {b01, b23, b45, b67};
      u16x8 pf[2] = {__builtin_bit_cast(u16x8, f1), __builtin_bit_cast(u16x8, f2)};
#pragma unroll
      for (int ks2 = 0; ks2 < 2; ++ks2) {
#pragma unroll
        for (int db = 0; db < 2; ++db) {
          const u16x8 vt = *(const u16x8*)(Vt + SWZ(db * 32 + l31, kb * 64 + ks2 * 32 + h * 16));
          accpv[db] = mfma32(pf[ks2], vt, accpv[db]);
        }
      }
    }
    __builtin_amdgcn_s_setprio(0);
    __builtin_amdgcn_sched_barrier(0);
    if (j + 2 < 16) {
      stageK(kt0 + j + 2, (j + 2) % 3);
      stageVT(kt0 + j + 2, (j + 2) % 3);
    }
  }

  // partial l: merge the two lane-halves (distinct k each), add once per q
  l_l += __shfl_xor(l_l, 32);
  if (h == 0) atomicAdd(&pl[bh * 2048 + qw + l31], l_l);

  // partial ctx: lane holds D[q = (r&3)+8(r>>2)+4h][dh = db*32+l31]; accumulate
#pragma unroll
  for (int db = 0; db < 2; ++db) {
#pragma unroll
    for (int r = 0; r < 16; ++r) {
      const int q = qw + (r & 3) + (r >> 2) * 8 + h * 4;
      atomicAdd(&out_ctx[(size_t)(b * 2048 + q) * 1024 + hh * 64 + db * 32 + l31],
                accpv[db][r]);
    }
  }
}

// ---------- normalize: ctx *= 1/l (in place), emit winv ----------
__global__ __launch_bounds__(256) void normalize_ctx(
    float* __restrict__ ctx, const float* __restrict__ pl, float* __restrict__ winv) {
  const int idx = blockIdx.x * 256 + threadIdx.x;  // < 1048576 (f32x4 units)
  const int row = idx >> 8;        // b*2048 + q
  const int c4 = idx & 255;        // f32x4 within row; head = c4>>4
  const int b = row >> 11, q = row & 2047, h = c4 >> 4;
  const float il = 1.0f / pl[(b * 16 + h) * 2048 + q];
  f32x4 v = ((const f32x4*)ctx)[idx];
  v[0] *= il; v[1] *= il; v[2] *= il; v[3] *= il;
  ((f32x4*)ctx)[idx] = v;
  if ((c4 & 15) == 0) winv[(b * 16 + h) * 2048 + q] = il;
}

// ---------- colsum (split-Q): c_k = sum_q exp2(s + mask*L) * winv_q ----------
// 256 thr = 4 waves; wave owns 32 k; block 128 k x 1024 q (16 Q-tiles).
// Grid 1024 = 32 bh x 16 ktile x 2 qh -> 4 blocks/CU, 16 waves/CU.
__global__ __launch_bounds__(256) void colsum_kernel(
    const u16* __restrict__ Qb, const u16* __restrict__ Kb,
    const float* __restrict__ maskg, const float* __restrict__ winv,
    float* __restrict__ out_cs) {
  __shared__ __align__(16) u16 Ql[3][4096];

  const int tid = threadIdx.x;
  const int w = tid >> 6, lane = tid & 63;
  const int lq = lane & 15, lg = lane >> 4;
  // XCD swizzle: 1024 blocks, 128/XCD; consecutive bids share (bh,qh) Q panel
  const int bid = (blockIdx.x & 7) * 128 + (blockIdx.x >> 3);
  const int ktile = bid & 15, qh = (bid >> 4) & 1, bh = bid >> 5;
  const int b = bh >> 4;
  const int kbase = ktile * 128 + w * 32;
  const int q0t = qh * 16;  // this block's 16 Q-tiles

  const u16* kp0 = Kb + ((size_t)bh * 2048 + kbase + lq) * 64 + lg * 8;
  const u16* kp1 = kp0 + 16 * 64;
  const u16x8 kb00 = *(const u16x8*)kp0, kb01 = *(const u16x8*)(kp0 + 32);
  const u16x8 kb10 = *(const u16x8*)kp1, kb11 = *(const u16x8*)(kp1 + 32);
  const float mvl0 = maskg[b * 2048 + kbase + lq] * LOG2E;
  const float mvl1 = maskg[b * 2048 + kbase + 16 + lq] * LOG2E;
  const float* wbase = winv + bh * 2048;
  const char* Qbase = (const char*)(Qb + (size_t)bh * 2048 * 64);

  const int r0 = tid >> 3;
  const int scol = ((tid & 7) * 16) ^ ((r0 & 7) << 4);
  auto stageQ = [&](int qt, int buf) {
    const char* src = Qbase + (size_t)(qt * 64) * 128;
    char* d = (char*)&Ql[buf][0] + w * 1024;
    gload_lds16(src + (size_t)r0 * 128 + scol, d);
    gload_lds16(src + (size_t)(r0 + 32) * 128 + scol, d + 4096);
  };

  float c0 = 0.f, c1 = 0.f;
  stageQ(q0t, 0);
  stageQ(q0t + 1, 1);
  for (int j = 0; j < 16; ++j) {
    const int qt = q0t + j;
    if (j < 15) vmwait<2>(); else vmwait<0>();
    __builtin_amdgcn_s_barrier();
    const char* Qt = (const char*)&Ql[j % 3][0];
    __builtin_amdgcn_s_setprio(1);
#pragma unroll
    for (int chunk = 0; chunk < 4; ++chunk) {
      const u16x8 qf0 = *(const u16x8*)(Qt + SWZ(chunk * 16 + lq, lg * 16));
      const u16x8 qf1 = *(const u16x8*)(Qt + SWZ(chunk * 16 + lq, 64 + lg * 16));
      f32x4 z = {0.f, 0.f, 0.f, 0.f};
      f32x4 s0 = mfma16(qf0, kb00, z);
      s0 = mfma16(qf1, kb01, s0);
      f32x4 s1 = mfma16(qf0, kb10, z);
      s1 = mfma16(qf1, kb11, s1);
      const f32x4 wv = *(const f32x4*)(wbase + qt * 64 + chunk * 16 + lg * 4);
#pragma unroll
      for (int r = 0; r < 4; ++r) {
        c0 += EXP2(s0[r] + mvl0) * wv[r];
        c1 += EXP2(s1[r] + mvl1) * wv[r];
      }
    }
    __builtin_amdgcn_s_setprio(0);
    __builtin_amdgcn_sched_barrier(0);
    if (j + 2 < 16) stageQ(q0t + j + 2, (j + 2) % 3);
  }
  c0 += __shfl_xor(c0, 16); c0 += __shfl_xor(c0, 32);
  c1 += __shfl_xor(c1, 16); c1 += __shfl_xor(c1, 32);
  if (lg == 0) {
    atomicAdd(&out_cs[b * 2048 + kbase + lq], c0);
    atomicAdd(&out_cs[b * 2048 + kbase + 16 + lq], c1);
  }
}

// ---------- launch ----------
extern "C" void kernel_launch(void* const* d_in, const int* in_sizes, int n_in,
                              void* d_out, int out_size, void* d_ws, size_t ws_size,
                              hipStream_t stream) {
  (void)in_sizes; (void)n_in; (void)out_size; (void)ws_size;
  const float* X    = (const float*)d_in[0];
  const float* mask = (const float*)d_in[1];
  const float* Wq   = (const float*)d_in[2];
  const float* bq   = (const float*)d_in[3];
  const float* Wk   = (const float*)d_in[4];
  const float* bk   = (const float*)d_in[5];
  const float* Wv   = (const float*)d_in[6];
  const float* bv   = (const float*)d_in[7];
  float* out = (float*)d_out;

  char* ws = (char*)d_ws;
  u16* Xb   = (u16*)(ws);                    // 8 MiB (dead after gemm)
  u16* Wcat = (u16*)(ws + 8388608);          // 6 MiB
  u16* Qb   = (u16*)(ws + 14680064);         // 8 MiB
  u16* Kb   = (u16*)(ws + 23068672);         // 8 MiB
  u16* VTb  = (u16*)(ws + 31457280);         // 8 MiB
  float* pl   = (float*)(ws + 39845888);     // 256 KiB partial l
  float* winv = (float*)(ws + 40108032);     // 256 KiB 1/l

  // zero entire output (ctx accumulated via atomics) + partial-l buffer
  hipMemsetAsync(out, 0, (4194304 + 4096) * sizeof(float), stream);
  hipMemsetAsync(pl, 0, 65536 * sizeof(float), stream);

  cast_f32_bf16<<<4096, 256, 0, stream>>>(X, Xb, 1048576);
  cast3_f32_bf16<<<3072, 256, 0, stream>>>(Wq, Wk, Wv, Wcat);

  gemm_qkv<<<dim3(24, 32), 256, 0, stream>>>(Xb, Wcat, bq, bk, bv, Qb, Kb, VTb);

  attn_split<<<512, 512, 0, stream>>>(Qb, Kb, VTb, mask, out, pl);
  normalize_ctx<<<4096, 256, 0, stream>>>(out, pl, winv);
  colsum_kernel<<<1024, 256, 0, stream>>>(Qb, Kb, mask, winv, out + 4194304);
}

// Round 12
// 147.072 us; speedup vs baseline: 1.1537x; 1.1537x over previous
//
#include <hip/hip_runtime.h>
#include <hip/hip_bf16.h>
#include <stdint.h>

typedef unsigned short u16;
typedef __attribute__((ext_vector_type(8))) unsigned short u16x8;
typedef __attribute__((ext_vector_type(4))) unsigned short u16x4;
typedef __attribute__((ext_vector_type(8))) __bf16 bf16x8;
typedef __attribute__((ext_vector_type(4))) float f32x4;
typedef __attribute__((ext_vector_type(16))) float f32x16;

#define LOG2E 1.44269504088896340736f

#if defined(__has_builtin)
#if __has_builtin(__builtin_amdgcn_exp2f)
#define EXP2(x) __builtin_amdgcn_exp2f(x)
#endif
#endif
#ifndef EXP2
#define EXP2(x) exp2f(x)
#endif

// ---------- helpers ----------
__device__ __forceinline__ f32x4 mfma16(u16x8 a, u16x8 b, f32x4 c) {
  return __builtin_amdgcn_mfma_f32_16x16x32_bf16(
      __builtin_bit_cast(bf16x8, a), __builtin_bit_cast(bf16x8, b), c, 0, 0, 0);
}

__device__ __forceinline__ f32x16 mfma32(u16x8 a, u16x8 b, f32x16 c) {
  return __builtin_amdgcn_mfma_f32_32x32x16_bf16(
      __builtin_bit_cast(bf16x8, a), __builtin_bit_cast(bf16x8, b), c, 0, 0, 0);
}

__device__ __forceinline__ u16 f2bf(float f) {
  unsigned u = __builtin_bit_cast(unsigned, f);
  return (u16)((u + 0x7fffu + ((u >> 16) & 1u)) >> 16);
}

__device__ __forceinline__ unsigned cvtpk(float a, float b) {
  unsigned r;
  asm volatile("v_cvt_pk_bf16_f32 %0, %1, %2" : "=v"(r) : "v"(a), "v"(b));
  return r;
}

// v_permlane32_swap_b32: a[32..63] <-> b[0..31]
__device__ __forceinline__ void pswap(unsigned& a, unsigned& b) {
  asm volatile("v_permlane32_swap_b32 %0, %1" : "+v"(a), "+v"(b));
}

__device__ __forceinline__ void gload_lds16(const void* g, void* l) {
  __builtin_amdgcn_global_load_lds(
      (__attribute__((address_space(1))) void*)const_cast<void*>(g),
      (__attribute__((address_space(3))) void*)l, 16, 0, 0);
}

template<int N> __device__ __forceinline__ void vmwait() {
  __builtin_amdgcn_sched_barrier(0);
  asm volatile("s_waitcnt vmcnt(%0)" :: "n"(N) : "memory");
  __builtin_amdgcn_sched_barrier(0);
}

#define SWZ(row, colbyte) ((((row) * 128) + (colbyte)) ^ (((row) & 7) << 4))

// ---------- fp32 -> bf16 casts ----------
__global__ void cast_f32_bf16(const float* __restrict__ src, u16* __restrict__ dst, int n4) {
  int i = blockIdx.x * blockDim.x + threadIdx.x;
  if (i < n4) {
    f32x4 v = ((const f32x4*)src)[i];
    u16x4 o;
    o[0] = f2bf(v[0]); o[1] = f2bf(v[1]); o[2] = f2bf(v[2]); o[3] = f2bf(v[3]);
    ((u16x4*)dst)[i] = o;
  }
}

__global__ void cast3_f32_bf16(const float* __restrict__ s0, const float* __restrict__ s1,
                               const float* __restrict__ s2, u16* __restrict__ dst) {
  const int seg = blockIdx.x >> 10;
  const int i = (blockIdx.x & 1023) * blockDim.x + threadIdx.x;
  const float* src = (seg == 0) ? s0 : ((seg == 1) ? s1 : s2);
  f32x4 v = ((const f32x4*)src)[i];
  u16x4 o;
  o[0] = f2bf(v[0]); o[1] = f2bf(v[1]); o[2] = f2bf(v[2]); o[3] = f2bf(v[3]);
  ((u16x4*)(dst + (size_t)seg * 1048576))[i] = o;
}

// ---------- fused QKV GEMM (3-buf, depth-2 prefetch, counted vmcnt) ----------
__global__ __launch_bounds__(256) void gemm_qkv(
    const u16* __restrict__ A, const u16* __restrict__ Bm,
    const float* __restrict__ bq, const float* __restrict__ bk, const float* __restrict__ bv,
    u16* __restrict__ Qb, u16* __restrict__ Kb, u16* __restrict__ VTb) {
  __shared__ __align__(16) u16 Asm[3][4096];
  __shared__ __align__(16) u16 Bsm[3][4096];
  const int tid = threadIdx.x;
  const int wave = tid >> 6, lane = tid & 63;
  const int lq = lane & 15, lg = lane >> 4;
  const int wr = wave >> 1, wc = wave & 1;
  const int lin = blockIdx.y * 24 + blockIdx.x;
  const int wg = (lin & 7) * 96 + (lin >> 3);
  const int m0 = (wg / 24) * 128, n0 = (wg % 24) * 128;

  f32x4 zero = {0.f, 0.f, 0.f, 0.f};
  f32x4 acc[4][4];
#pragma unroll
  for (int mi = 0; mi < 4; ++mi)
#pragma unroll
    for (int ni = 0; ni < 4; ++ni) acc[mi][ni] = zero;

  auto stage = [&](int kt, int buf) {
    const int k0 = kt * 32;
#pragma unroll
    for (int c = 0; c < 2; ++c) {
      const int idx = wave * 2 + c;
      const u16* ga = A + (size_t)(m0 + idx * 16 + (lane >> 2)) * 1024 + k0 + (lane & 3) * 8;
      gload_lds16(ga, (char*)&Asm[buf][0] + idx * 1024);
      const u16* gb = Bm + (size_t)(n0 + idx * 16 + (lane >> 2)) * 1024 + k0 + (lane & 3) * 8;
      gload_lds16(gb, (char*)&Bsm[buf][0] + idx * 1024);
    }
  };

  stage(0, 0);
  stage(1, 1);
  for (int kt = 0; kt < 32; ++kt) {
    if (kt < 31) vmwait<4>(); else vmwait<0>();
    __builtin_amdgcn_s_barrier();
    if (kt + 2 < 32) stage(kt + 2, (kt + 2) % 3);
    const int cur = kt % 3;

    __builtin_amdgcn_s_setprio(1);
    u16x8 af[4], bfr[4];
#pragma unroll
    for (int mi = 0; mi < 4; ++mi)
      af[mi] = *(const u16x8*)&Asm[cur][(wr * 64 + mi * 16 + lq) * 32 + lg * 8];
#pragma unroll
    for (int ni = 0; ni < 4; ++ni)
      bfr[ni] = *(const u16x8*)&Bsm[cur][(wc * 64 + ni * 16 + lq) * 32 + lg * 8];
#pragma unroll
    for (int mi = 0; mi < 4; ++mi)
#pragma unroll
      for (int ni = 0; ni < 4; ++ni)
        acc[mi][ni] = mfma16(af[mi], bfr[ni], acc[mi][ni]);
    __builtin_amdgcn_s_setprio(0);
  }

  const int which = n0 >> 10;
  const float* bias = (which == 0) ? bq : ((which == 1) ? bk : bv);
  const float scl = (which == 0) ? (0.125f * LOG2E) : 1.0f;
#pragma unroll
  for (int mi = 0; mi < 4; ++mi) {
    const int m = m0 + wr * 64 + mi * 16 + lg * 4;
    const int bb = m >> 11;
    const int s = m & 2047;
#pragma unroll
    for (int ni = 0; ni < 4; ++ni) {
      const int n = n0 + wc * 64 + ni * 16 + lq;
      const int d = n & 1023;
      const int h = d >> 6, dh = d & 63;
      const float bi = bias[d];
#pragma unroll
      for (int r = 0; r < 4; ++r) {
        float v = (acc[mi][ni][r] + bi) * scl;
        if (which == 2)
          VTb[(((size_t)bb * 16 + h) * 64 + dh) * 2048 + (size_t)(s + r)] = f2bf(v);
        else {
          u16* dst = (which == 0) ? Qb : Kb;
          dst[(((size_t)bb * 16 + h) * 2048 + (size_t)(s + r)) * 64 + dh] = f2bf(v);
        }
      }
    }
  }
}

// ---------- attention: in-block split-K pairs, 32x32 MFMA, in-register P ----------
// 512 thr = 8 waves: wave w -> k-half hf=w>>2, q-subtile p=w&3 (32 q each).
// Grid 512 = 32 bh x 16 qt -> 2 blocks/CU, 16 waves/CU. LDS merge, no atomics.
__global__ __launch_bounds__(512) void attn_pair(
    const u16* __restrict__ Qb, const u16* __restrict__ Kb, const u16* __restrict__ VTb,
    const float* __restrict__ maskg, float* __restrict__ out_ctx, float* __restrict__ winv) {
  __shared__ __align__(16) u16 Kl[2][2][4096];   // [half][buf] 32 KB
  __shared__ __align__(16) u16 VTl[2][2][4096];  // 32 KB

  const int tid = threadIdx.x;
  const int w = tid >> 6, lane = tid & 63;
  const int l31 = lane & 31, h = lane >> 5;
  const int hf = w >> 2, p = w & 3;
  // XCD swizzle: 512 blocks, 64/XCD -> 4 consecutive bh per XCD
  const int bid = (blockIdx.x & 7) * 64 + (blockIdx.x >> 3);
  const int qt = bid & 15, bh = bid >> 4;
  const int b = bh >> 4, hh = bh & 15;
  const int qw = qt * 128 + p * 32;   // this wave's 32 q rows
  const int kt0 = hf * 16;            // this wave's 16 k-tiles (of 64 k)

  // Q frags: lane holds Q[qw+l31][dh = 16dq + 8h + j]
  const u16* qp = Qb + ((size_t)bh * 2048 + qw + l31) * 64 + h * 8;
  u16x8 qa[4];
#pragma unroll
  for (int dq = 0; dq < 4; ++dq) qa[dq] = *(const u16x8*)(qp + dq * 16);

  const char* Kbase = (const char*)(Kb + (size_t)bh * 2048 * 64);
  const char* VTbase = (const char*)(VTb + (size_t)bh * 64 * 2048);
  const float* mbase = maskg + b * 2048;

  // staging: per half (256 threads), 8KB tiles, 2 chunks/thread (rows srow, srow+32)
  const int t8 = tid & 255;
  const int srow = t8 >> 3;                              // 0..31
  const int scol = ((t8 & 7) * 16) ^ ((srow & 7) << 4);  // pre-swizzled source col
  auto stage = [&](int kt, int buf) {                    // 4 loads/thread
    const char* ksrc = Kbase + (size_t)(kt * 64) * 128;
    char* kd = (char*)&Kl[hf][buf][0] + (w & 3) * 1024;
    gload_lds16(ksrc + (size_t)srow * 128 + scol, kd);
    gload_lds16(ksrc + (size_t)(srow + 32) * 128 + scol, kd + 4096);
    const char* vsrc = VTbase + (size_t)kt * 128;
    char* vd = (char*)&VTl[hf][buf][0] + (w & 3) * 1024;
    gload_lds16(vsrc + (size_t)srow * 4096 + scol, vd);
    gload_lds16(vsrc + (size_t)(srow + 32) * 4096 + scol, vd + 4096);
  };

  f32x16 accpv[2];
#pragma unroll
  for (int db = 0; db < 2; ++db)
#pragma unroll
    for (int r = 0; r < 16; ++r) accpv[db][r] = 0.f;
  float l_l = 0.f;

  stage(kt0, 0);
  for (int j = 0; j < 16; ++j) {
    const int kt = kt0 + j;
    vmwait<0>();
    __builtin_amdgcn_s_barrier();
    const int cur = j & 1;
    const char* Kt = (const char*)&Kl[hf][cur][0];
    const char* Vt = (const char*)&VTl[hf][cur][0];

    __builtin_amdgcn_s_setprio(1);
#pragma unroll
    for (int kb = 0; kb < 2; ++kb) {
      // QK^T: S[k = kt*64 + kb*32 + (r&3)+8(r>>2)+4h][q = l31]
      f32x16 s;
#pragma unroll
      for (int r = 0; r < 16; ++r) s[r] = 0.f;
#pragma unroll
      for (int dq = 0; dq < 4; ++dq) {
        const u16x8 ka = *(const u16x8*)(Kt + SWZ(kb * 32 + l31, dq * 32 + h * 16));
        s = mfma32(ka, qa[dq], s);
      }
      float pv[16];
#pragma unroll
      for (int g = 0; g < 4; ++g) {
        const f32x4 mv = *(const f32x4*)(mbase + kt * 64 + kb * 32 + g * 8 + h * 4);
#pragma unroll
        for (int j2 = 0; j2 < 4; ++j2)
          pv[g * 4 + j2] = EXP2(fmaf(mv[j2], LOG2E, s[g * 4 + j2]));
      }
      l_l += ((pv[0] + pv[1]) + (pv[2] + pv[3])) + ((pv[4] + pv[5]) + (pv[6] + pv[7])) +
             ((pv[8] + pv[9]) + (pv[10] + pv[11])) + ((pv[12] + pv[13]) + (pv[14] + pv[15]));
      // P -> PV A-frags: pairs packed, lane-halves swapped
      unsigned a01 = cvtpk(pv[0], pv[1]), a23 = cvtpk(pv[2], pv[3]);
      unsigned a45 = cvtpk(pv[4], pv[5]), a67 = cvtpk(pv[6], pv[7]);
      unsigned b01 = cvtpk(pv[8], pv[9]), b23 = cvtpk(pv[10], pv[11]);
      unsigned b45 = cvtpk(pv[12], pv[13]), b67 = cvtpk(pv[14], pv[15]);
      pswap(a01, a45); pswap(a23, a67);
      pswap(b01, b45); pswap(b23, b67);
      uint4 f1 = {a01, a23, a45, a67};
      uint4 f2 = {b01, b23, b45, b67};
      u16x8 pf[2] = {__builtin_bit_cast(u16x8, f1), __builtin_bit_cast(u16x8, f2)};
#pragma unroll
      for (int ks2 = 0; ks2 < 2; ++ks2) {
#pragma unroll
        for (int db = 0; db < 2; ++db) {
          const u16x8 vt = *(const u16x8*)(Vt + SWZ(db * 32 + l31, kb * 64 + ks2 * 32 + h * 16));
          accpv[db] = mfma32(pf[ks2], vt, accpv[db]);
        }
      }
    }
    __builtin_amdgcn_s_setprio(0);
    __builtin_amdgcn_sched_barrier(0);
    if (j + 1 < 16) stage(kt0 + j + 1, cur ^ 1);
  }

  // merge the two lane-halves of l (distinct k each)
  l_l += __shfl_xor(l_l, 32);

  // ---- pair merge through LDS (staging buffers are dead now) ----
  __syncthreads();
  float* pairctx = (float*)&Kl[0][0][0];   // 4 pairs x 32q x 64dh fp32 = 32 KB
  float* pairl   = (float*)&VTl[0][0][0];  // 4 pairs x 32 fp32
  if (hf == 1) {
#pragma unroll
    for (int db = 0; db < 2; ++db)
#pragma unroll
      for (int r = 0; r < 16; ++r) {
        const int q = (r & 3) + (r >> 2) * 8 + h * 4;
        pairctx[p * 2048 + q * 64 + db * 32 + l31] = accpv[db][r];
      }
    if (h == 0) pairl[p * 32 + l31] = l_l;
  }
  __syncthreads();
  if (hf == 0) {
    const float lt = l_l + pairl[p * 32 + l31];  // total l for q = qw + l31
    const float il = 1.0f / lt;
    if (h == 0) winv[bh * 2048 + qw + l31] = il;
#pragma unroll
    for (int r = 0; r < 16; ++r) {
      const int q = (r & 3) + (r >> 2) * 8 + h * 4;
      const float ilr = __shfl(il, q);  // il lives at lane l31 == q
      const size_t row = (size_t)(b * 2048 + qw + q) * 1024 + hh * 64;
      out_ctx[row + l31] =
          (accpv[0][r] + pairctx[p * 2048 + q * 64 + l31]) * ilr;
      out_ctx[row + 32 + l31] =
          (accpv[1][r] + pairctx[p * 2048 + q * 64 + 32 + l31]) * ilr;
    }
  }
}

// ---------- colsum (split-Q): c_k = sum_q exp2(s + mask*L) * winv_q ----------
// 256 thr = 4 waves; wave owns 32 k; block 128 k x 1024 q (16 Q-tiles).
// Grid 1024 -> 4 blocks/CU, 16 waves/CU.
__global__ __launch_bounds__(256) void colsum_kernel(
    const u16* __restrict__ Qb, const u16* __restrict__ Kb,
    const float* __restrict__ maskg, const float* __restrict__ winv,
    float* __restrict__ out_cs) {
  __shared__ __align__(16) u16 Ql[3][4096];

  const int tid = threadIdx.x;
  const int w = tid >> 6, lane = tid & 63;
  const int lq = lane & 15, lg = lane >> 4;
  const int bid = (blockIdx.x & 7) * 128 + (blockIdx.x >> 3);
  const int ktile = bid & 15, qh = (bid >> 4) & 1, bh = bid >> 5;
  const int b = bh >> 4;
  const int kbase = ktile * 128 + w * 32;
  const int q0t = qh * 16;

  const u16* kp0 = Kb + ((size_t)bh * 2048 + kbase + lq) * 64 + lg * 8;
  const u16* kp1 = kp0 + 16 * 64;
  const u16x8 kb00 = *(const u16x8*)kp0, kb01 = *(const u16x8*)(kp0 + 32);
  const u16x8 kb10 = *(const u16x8*)kp1, kb11 = *(const u16x8*)(kp1 + 32);
  const float mvl0 = maskg[b * 2048 + kbase + lq] * LOG2E;
  const float mvl1 = maskg[b * 2048 + kbase + 16 + lq] * LOG2E;
  const float* wbase = winv + bh * 2048;
  const char* Qbase = (const char*)(Qb + (size_t)bh * 2048 * 64);

  const int r0 = tid >> 3;
  const int scol = ((tid & 7) * 16) ^ ((r0 & 7) << 4);
  auto stageQ = [&](int qt, int buf) {
    const char* src = Qbase + (size_t)(qt * 64) * 128;
    char* d = (char*)&Ql[buf][0] + w * 1024;
    gload_lds16(src + (size_t)r0 * 128 + scol, d);
    gload_lds16(src + (size_t)(r0 + 32) * 128 + scol, d + 4096);
  };

  float c0 = 0.f, c1 = 0.f;
  stageQ(q0t, 0);
  stageQ(q0t + 1, 1);
  for (int j = 0; j < 16; ++j) {
    const int qt = q0t + j;
    if (j < 15) vmwait<2>(); else vmwait<0>();
    __builtin_amdgcn_s_barrier();
    const char* Qt = (const char*)&Ql[j % 3][0];
    __builtin_amdgcn_s_setprio(1);
#pragma unroll
    for (int chunk = 0; chunk < 4; ++chunk) {
      const u16x8 qf0 = *(const u16x8*)(Qt + SWZ(chunk * 16 + lq, lg * 16));
      const u16x8 qf1 = *(const u16x8*)(Qt + SWZ(chunk * 16 + lq, 64 + lg * 16));
      f32x4 z = {0.f, 0.f, 0.f, 0.f};
      f32x4 s0 = mfma16(qf0, kb00, z);
      s0 = mfma16(qf1, kb01, s0);
      f32x4 s1 = mfma16(qf0, kb10, z);
      s1 = mfma16(qf1, kb11, s1);
      const f32x4 wv = *(const f32x4*)(wbase + qt * 64 + chunk * 16 + lg * 4);
#pragma unroll
      for (int r = 0; r < 4; ++r) {
        c0 += EXP2(s0[r] + mvl0) * wv[r];
        c1 += EXP2(s1[r] + mvl1) * wv[r];
      }
    }
    __builtin_amdgcn_s_setprio(0);
    __builtin_amdgcn_sched_barrier(0);
    if (j + 2 < 16) stageQ(q0t + j + 2, (j + 2) % 3);
  }
  c0 += __shfl_xor(c0, 16); c0 += __shfl_xor(c0, 32);
  c1 += __shfl_xor(c1, 16); c1 += __shfl_xor(c1, 32);
  if (lg == 0) {
    atomicAdd(&out_cs[b * 2048 + kbase + lq], c0);
    atomicAdd(&out_cs[b * 2048 + kbase + 16 + lq], c1);
  }
}

// ---------- launch ----------
extern "C" void kernel_launch(void* const* d_in, const int* in_sizes, int n_in,
                              void* d_out, int out_size, void* d_ws, size_t ws_size,
                              hipStream_t stream) {
  (void)in_sizes; (void)n_in; (void)out_size; (void)ws_size;
  const float* X    = (const float*)d_in[0];
  const float* mask = (const float*)d_in[1];
  const float* Wq   = (const float*)d_in[2];
  const float* bq   = (const float*)d_in[3];
  const float* Wk   = (const float*)d_in[4];
  const float* bk   = (const float*)d_in[5];
  const float* Wv   = (const float*)d_in[6];
  const float* bv   = (const float*)d_in[7];
  float* out = (float*)d_out;

  char* ws = (char*)d_ws;
  u16* Xb   = (u16*)(ws);                    // 8 MiB (dead after gemm)
  u16* Wcat = (u16*)(ws + 8388608);          // 6 MiB
  u16* Qb   = (u16*)(ws + 14680064);         // 8 MiB
  u16* Kb   = (u16*)(ws + 23068672);         // 8 MiB
  u16* VTb  = (u16*)(ws + 31457280);         // 8 MiB
  float* winv = (float*)(ws + 39845888);     // 256 KiB

  // zero only the colsum region (ctx fully overwritten by attn_pair)
  hipMemsetAsync(out + 4194304, 0, 4096 * sizeof(float), stream);

  cast_f32_bf16<<<4096, 256, 0, stream>>>(X, Xb, 1048576);
  cast3_f32_bf16<<<3072, 256, 0, stream>>>(Wq, Wk, Wv, Wcat);

  gemm_qkv<<<dim3(24, 32), 256, 0, stream>>>(Xb, Wcat, bq, bk, bv, Qb, Kb, VTb);

  attn_pair<<<512, 512, 0, stream>>>(Qb, Kb, VTb, mask, out, winv);
  colsum_kernel<<<1024, 256, 0, stream>>>(Qb, Kb, mask, winv, out + 4194304);
}

// Round 13
// 143.230 us; speedup vs baseline: 1.1846x; 1.0268x over previous
//
#include <hip/hip_runtime.h>
#include <hip/hip_bf16.h>
#include <stdint.h>

typedef unsigned short u16;
typedef __attribute__((ext_vector_type(8))) unsigned short u16x8;
typedef __attribute__((ext_vector_type(4))) unsigned short u16x4;
typedef __attribute__((ext_vector_type(8))) __bf16 bf16x8;
typedef __attribute__((ext_vector_type(4))) float f32x4;
typedef __attribute__((ext_vector_type(16))) float f32x16;

#define LOG2E 1.44269504088896340736f

#if defined(__has_builtin)
#if __has_builtin(__builtin_amdgcn_exp2f)
#define EXP2(x) __builtin_amdgcn_exp2f(x)
#endif
#endif
#ifndef EXP2
#define EXP2(x) exp2f(x)
#endif

// ---------- helpers ----------
__device__ __forceinline__ f32x4 mfma16(u16x8 a, u16x8 b, f32x4 c) {
  return __builtin_amdgcn_mfma_f32_16x16x32_bf16(
      __builtin_bit_cast(bf16x8, a), __builtin_bit_cast(bf16x8, b), c, 0, 0, 0);
}

__device__ __forceinline__ f32x16 mfma32(u16x8 a, u16x8 b, f32x16 c) {
  return __builtin_amdgcn_mfma_f32_32x32x16_bf16(
      __builtin_bit_cast(bf16x8, a), __builtin_bit_cast(bf16x8, b), c, 0, 0, 0);
}

__device__ __forceinline__ u16 f2bf(float f) {
  unsigned u = __builtin_bit_cast(unsigned, f);
  return (u16)((u + 0x7fffu + ((u >> 16) & 1u)) >> 16);
}

__device__ __forceinline__ unsigned cvtpk(float a, float b) {
  unsigned r;
  asm volatile("v_cvt_pk_bf16_f32 %0, %1, %2" : "=v"(r) : "v"(a), "v"(b));
  return r;
}

// v_permlane32_swap_b32: a[32..63] <-> b[0..31]
__device__ __forceinline__ void pswap(unsigned& a, unsigned& b) {
  asm volatile("v_permlane32_swap_b32 %0, %1" : "+v"(a), "+v"(b));
}

__device__ __forceinline__ void gload_lds16(const void* g, void* l) {
  __builtin_amdgcn_global_load_lds(
      (__attribute__((address_space(1))) void*)const_cast<void*>(g),
      (__attribute__((address_space(3))) void*)l, 16, 0, 0);
}

template<int N> __device__ __forceinline__ void vmwait() {
  __builtin_amdgcn_sched_barrier(0);
  asm volatile("s_waitcnt vmcnt(%0)" :: "n"(N) : "memory");
  __builtin_amdgcn_sched_barrier(0);
}

#define SWZ(row, colbyte) ((((row) * 128) + (colbyte)) ^ (((row) & 7) << 4))

// ---------- merged fp32 -> bf16 casts (X + 3 W's in one launch) ----------
__global__ void cast_all(const float* __restrict__ X,
                         const float* __restrict__ s0, const float* __restrict__ s1,
                         const float* __restrict__ s2,
                         u16* __restrict__ Xb, u16* __restrict__ Wcat) {
  const int bid = blockIdx.x;
  const float* src;
  u16* dst;
  int i;
  if (bid < 4096) {                       // X: 1048576 f32x4 units
    src = X; dst = Xb;
    i = bid * 256 + threadIdx.x;
  } else {                                // W: 3 x 262144 units
    const int wb = bid - 4096;
    const int seg = wb >> 10;
    src = (seg == 0) ? s0 : ((seg == 1) ? s1 : s2);
    dst = Wcat + (size_t)seg * 1048576;
    i = (wb & 1023) * 256 + threadIdx.x;
  }
  f32x4 v = ((const f32x4*)src)[i];
  u16x4 o;
  o[0] = f2bf(v[0]); o[1] = f2bf(v[1]); o[2] = f2bf(v[2]); o[3] = f2bf(v[3]);
  ((u16x4*)dst)[i] = o;
}

// ---------- fused QKV GEMM (3-buf, depth-2, counted vmcnt, swizzled LDS) ----------
// LDS tile [128 rows][32 k] stored as 64 lines x 128B; within a line the 8
// 16B-slots are XOR-permuted by (line&7) -> A/B fragment reads conflict-free.
__global__ __launch_bounds__(256) void gemm_qkv(
    const u16* __restrict__ A, const u16* __restrict__ Bm,
    const float* __restrict__ bq, const float* __restrict__ bk, const float* __restrict__ bv,
    u16* __restrict__ Qb, u16* __restrict__ Kb, u16* __restrict__ VTb) {
  __shared__ __align__(16) u16 Asm[3][4096];
  __shared__ __align__(16) u16 Bsm[3][4096];
  const int tid = threadIdx.x;
  const int wave = tid >> 6, lane = tid & 63;
  const int lq = lane & 15, lg = lane >> 4;
  const int wr = wave >> 1, wc = wave & 1;
  const int lin = blockIdx.y * 24 + blockIdx.x;
  const int wg = (lin & 7) * 96 + (lin >> 3);
  const int m0 = (wg / 24) * 128, n0 = (wg % 24) * 128;

  f32x4 zero = {0.f, 0.f, 0.f, 0.f};
  f32x4 acc[4][4];
#pragma unroll
  for (int mi = 0; mi < 4; ++mi)
#pragma unroll
    for (int ni = 0; ni < 4; ++ni) acc[mi][ni] = zero;

  // staging chunk -> logical (row, 16B-k-unit), inverse of the read swizzle
  int rA0, k16A0, rA1, k16A1;
  {
    const int cc0 = wave * 128 + lane;
    const int ln0 = cc0 >> 3, sp0 = (cc0 & 7) ^ (ln0 & 7);
    rA0 = ln0 * 2 + (sp0 >> 2); k16A0 = sp0 & 3;
    const int cc1 = cc0 + 64;
    const int ln1 = cc1 >> 3, sp1 = (cc1 & 7) ^ (ln1 & 7);
    rA1 = ln1 * 2 + (sp1 >> 2); k16A1 = sp1 & 3;
  }

  auto stage = [&](int kt, int buf) {   // 4 loads/thread
    const int kk = kt * 32;
    gload_lds16(A + (size_t)(m0 + rA0) * 1024 + kk + k16A0 * 8,
                (char*)&Asm[buf][0] + (wave * 2 + 0) * 1024);
    gload_lds16(A + (size_t)(m0 + rA1) * 1024 + kk + k16A1 * 8,
                (char*)&Asm[buf][0] + (wave * 2 + 1) * 1024);
    gload_lds16(Bm + (size_t)(n0 + rA0) * 1024 + kk + k16A0 * 8,
                (char*)&Bsm[buf][0] + (wave * 2 + 0) * 1024);
    gload_lds16(Bm + (size_t)(n0 + rA1) * 1024 + kk + k16A1 * 8,
                (char*)&Bsm[buf][0] + (wave * 2 + 1) * 1024);
  };

  stage(0, 0);
  stage(1, 1);
  for (int kt = 0; kt < 32; ++kt) {
    if (kt < 31) vmwait<4>(); else vmwait<0>();
    __builtin_amdgcn_s_barrier();
    if (kt + 2 < 32) stage(kt + 2, (kt + 2) % 3);
    const int cur = kt % 3;

    __builtin_amdgcn_s_setprio(1);
    u16x8 af[4], bfr[4];
#pragma unroll
    for (int mi = 0; mi < 4; ++mi) {
      const int rA = wr * 64 + mi * 16 + lq;
      const int lnA = rA >> 1;
      const int spA = ((rA & 1) << 2) | lg;
      af[mi] = *(const u16x8*)((const char*)&Asm[cur][0] +
                               lnA * 128 + ((spA ^ (lnA & 7)) << 4));
    }
#pragma unroll
    for (int ni = 0; ni < 4; ++ni) {
      const int rB = wc * 64 + ni * 16 + lq;
      const int lnB = rB >> 1;
      const int spB = ((rB & 1) << 2) | lg;
      bfr[ni] = *(const u16x8*)((const char*)&Bsm[cur][0] +
                                lnB * 128 + ((spB ^ (lnB & 7)) << 4));
    }
#pragma unroll
    for (int mi = 0; mi < 4; ++mi)
#pragma unroll
      for (int ni = 0; ni < 4; ++ni)
        acc[mi][ni] = mfma16(af[mi], bfr[ni], acc[mi][ni]);
    __builtin_amdgcn_s_setprio(0);
  }

  const int which = n0 >> 10;
  const float* bias = (which == 0) ? bq : ((which == 1) ? bk : bv);
  const float scl = (which == 0) ? (0.125f * LOG2E) : 1.0f;
#pragma unroll
  for (int mi = 0; mi < 4; ++mi) {
    const int m = m0 + wr * 64 + mi * 16 + lg * 4;
    const int bb = m >> 11;
    const int s = m & 2047;
#pragma unroll
    for (int ni = 0; ni < 4; ++ni) {
      const int n = n0 + wc * 64 + ni * 16 + lq;
      const int d = n & 1023;
      const int h = d >> 6, dh = d & 63;
      const float bi = bias[d];
#pragma unroll
      for (int r = 0; r < 4; ++r) {
        float v = (acc[mi][ni][r] + bi) * scl;
        if (which == 2)
          VTb[(((size_t)bb * 16 + h) * 64 + dh) * 2048 + (size_t)(s + r)] = f2bf(v);
        else {
          u16* dst = (which == 0) ? Qb : Kb;
          dst[(((size_t)bb * 16 + h) * 2048 + (size_t)(s + r)) * 64 + dh] = f2bf(v);
        }
      }
    }
  }
}

// ---------- attention: pair-split, 32x32 MFMA, K-tile 32, 3-buf counted vmcnt ----
// 512 thr = 8 waves: hf=w>>2 (k-half), p=w&3 (q-subtile of 32). Grid 512 ->
// 2 blocks/CU, 16 waves/CU. Depth-2 prefetch with vmwait<2>; LDS pair merge.
__global__ __launch_bounds__(512) void attn_pair(
    const u16* __restrict__ Qb, const u16* __restrict__ Kb, const u16* __restrict__ VTb,
    const float* __restrict__ maskg, float* __restrict__ out_ctx, float* __restrict__ winv) {
  // smem: K[hf][buf] @ hf*12288+buf*4096 (24KB), VT @ 24576+... (24KB), pairl @ 49152
  __shared__ __align__(16) char smem[49664];

  const int tid = threadIdx.x;
  const int w = tid >> 6, lane = tid & 63;
  const int l31 = lane & 31, h = lane >> 5;
  const int hf = w >> 2, p = w & 3;
  const int bid = (blockIdx.x & 7) * 64 + (blockIdx.x >> 3);
  const int qt = bid & 15, bh = bid >> 4;
  const int b = bh >> 4, hh = bh & 15;
  const int qw = qt * 128 + p * 32;

  // Q frags: lane holds Q[qw+l31][dh = 16dq + 8h + j]
  const u16* qp = Qb + ((size_t)bh * 2048 + qw + l31) * 64 + h * 8;
  u16x8 qa[4];
#pragma unroll
  for (int dq = 0; dq < 4; ++dq) qa[dq] = *(const u16x8*)(qp + dq * 16);

  const char* KbaseG = (const char*)(Kb + (size_t)bh * 2048 * 64);
  const char* VTbaseG = (const char*)(VTb + (size_t)bh * 64 * 2048);
  const float* mbase = maskg + b * 2048;

  // staging (per half: 256 threads, 1 K-chunk + 1 VT-chunk each)
  const int t8 = tid & 255;
  const int srowK = t8 >> 3;                                // K row 0..31 (128B rows)
  const int scolK = ((t8 & 7) * 16) ^ ((srowK & 7) << 4);   // inverse swizzle
  const int lineV = t8 >> 3;                                // VT line 0..31 (2 dh rows)
  const int spV = (t8 & 7) ^ (lineV & 7);
  const int dhV = lineV * 2 + (spV >> 2);
  const int kbV = (spV & 3) * 16;

  auto stage = [&](int kt, int buf) {   // 2 loads/thread
    char* kd = smem + hf * 12288 + buf * 4096 + (w & 3) * 1024;
    gload_lds16(KbaseG + (size_t)(kt * 32 + srowK) * 128 + scolK, kd);
    char* vd = smem + 24576 + hf * 12288 + buf * 4096 + (w & 3) * 1024;
    gload_lds16(VTbaseG + (size_t)dhV * 4096 + (size_t)kt * 64 + kbV, vd);
  };

  f32x16 accpv[2];
#pragma unroll
  for (int db = 0; db < 2; ++db)
#pragma unroll
    for (int r = 0; r < 16; ++r) accpv[db][r] = 0.f;
  float l_l = 0.f;

  const int kt0 = hf * 32;
  stage(kt0, 0);
  stage(kt0 + 1, 1);
  for (int j = 0; j < 32; ++j) {
    const int kt = kt0 + j;
    if (j < 31) vmwait<2>(); else vmwait<0>();
    __builtin_amdgcn_s_barrier();
    const char* Kt = smem + hf * 12288 + (j % 3) * 4096;
    const char* Vt = smem + 24576 + hf * 12288 + (j % 3) * 4096;

    __builtin_amdgcn_s_setprio(1);
    // QK^T: S[k = kt*32 + (r&3)+8(r>>2)+4h][q = l31]
    f32x16 s;
#pragma unroll
    for (int r = 0; r < 16; ++r) s[r] = 0.f;
#pragma unroll
    for (int dq = 0; dq < 4; ++dq) {
      const u16x8 ka = *(const u16x8*)(Kt + SWZ(l31, dq * 32 + h * 16));
      s = mfma32(ka, qa[dq], s);
    }
    float pv[16];
#pragma unroll
    for (int g = 0; g < 4; ++g) {
      const f32x4 mv = *(const f32x4*)(mbase + kt * 32 + g * 8 + h * 4);
#pragma unroll
      for (int j2 = 0; j2 < 4; ++j2)
        pv[g * 4 + j2] = EXP2(fmaf(mv[j2], LOG2E, s[g * 4 + j2]));
    }
    l_l += ((pv[0] + pv[1]) + (pv[2] + pv[3])) + ((pv[4] + pv[5]) + (pv[6] + pv[7])) +
           ((pv[8] + pv[9]) + (pv[10] + pv[11])) + ((pv[12] + pv[13]) + (pv[14] + pv[15]));
    // P -> PV A-frags: pairs packed, lane-halves swapped
    unsigned a01 = cvtpk(pv[0], pv[1]), a23 = cvtpk(pv[2], pv[3]);
    unsigned a45 = cvtpk(pv[4], pv[5]), a67 = cvtpk(pv[6], pv[7]);
    unsigned b01 = cvtpk(pv[8], pv[9]), b23 = cvtpk(pv[10], pv[11]);
    unsigned b45 = cvtpk(pv[12], pv[13]), b67 = cvtpk(pv[14], pv[15]);
    pswap(a01, a45); pswap(a23, a67);  // frag ks2=0: k = kt*32 + [0,16)
    pswap(b01, b45); pswap(b23, b67);  // frag ks2=1: k = kt*32 + [16,32)
    uint4 f1 = {a01, a23, a45, a67};
    uint4 f2 = {b01, b23, b45, b67};
    u16x8 pf[2] = {__builtin_bit_cast(u16x8, f1), __builtin_bit_cast(u16x8, f2)};
    // PV: ctx[q][dh] += P[q][k] * VT[dh][k]  (pair-line swizzled VT reads)
#pragma unroll
    for (int ks2 = 0; ks2 < 2; ++ks2) {
#pragma unroll
      for (int db = 0; db < 2; ++db) {
        const int rowV = db * 32 + l31;
        const int lnV = rowV >> 1;
        const int sV = ((rowV & 1) << 2) | (ks2 << 1) | h;
        const u16x8 vt = *(const u16x8*)(Vt + lnV * 128 + ((sV ^ (lnV & 7)) << 4));
        accpv[db] = mfma32(pf[ks2], vt, accpv[db]);
      }
    }
    __builtin_amdgcn_s_setprio(0);
    __builtin_amdgcn_sched_barrier(0);
    if (j + 2 < 32) stage(kt0 + j + 2, (j + 2) % 3);
  }

  // merge the two lane-halves of l (distinct k each)
  l_l += __shfl_xor(l_l, 32);

  // ---- pair merge through LDS (staging buffers dead) ----
  __syncthreads();
  float* pairctx = (float*)smem;             // 4 p x 32q x 64dh = 32 KB
  float* pairl = (float*)(smem + 49152);     // 4 p x 32
  if (hf == 1) {
#pragma unroll
    for (int db = 0; db < 2; ++db)
#pragma unroll
      for (int r = 0; r < 16; ++r) {
        const int q = (r & 3) + (r >> 2) * 8 + h * 4;
        pairctx[p * 2048 + q * 64 + db * 32 + l31] = accpv[db][r];
      }
    if (h == 0) pairl[p * 32 + l31] = l_l;
  }
  __syncthreads();
  if (hf == 0) {
    const float lt = l_l + pairl[p * 32 + l31];
    const float il = 1.0f / lt;
    if (h == 0) winv[bh * 2048 + qw + l31] = il;
#pragma unroll
    for (int r = 0; r < 16; ++r) {
      const int q = (r & 3) + (r >> 2) * 8 + h * 4;
      const float ilr = __shfl(il, q);
      const size_t row = (size_t)(b * 2048 + qw + q) * 1024 + hh * 64;
      out_ctx[row + l31] = (accpv[0][r] + pairctx[p * 2048 + q * 64 + l31]) * ilr;
      out_ctx[row + 32 + l31] = (accpv[1][r] + pairctx[p * 2048 + q * 64 + 32 + l31]) * ilr;
    }
  }
}

// ---------- colsum (split-Q): c_k = sum_q exp2(s + mask*L) * winv_q ----------
__global__ __launch_bounds__(256) void colsum_kernel(
    const u16* __restrict__ Qb, const u16* __restrict__ Kb,
    const float* __restrict__ maskg, const float* __restrict__ winv,
    float* __restrict__ out_cs) {
  __shared__ __align__(16) u16 Ql[3][4096];

  const int tid = threadIdx.x;
  const int w = tid >> 6, lane = tid & 63;
  const int lq = lane & 15, lg = lane >> 4;
  const int bid = (blockIdx.x & 7) * 128 + (blockIdx.x >> 3);
  const int ktile = bid & 15, qh = (bid >> 4) & 1, bh = bid >> 5;
  const int b = bh >> 4;
  const int kbase = ktile * 128 + w * 32;
  const int q0t = qh * 16;

  const u16* kp0 = Kb + ((size_t)bh * 2048 + kbase + lq) * 64 + lg * 8;
  const u16* kp1 = kp0 + 16 * 64;
  const u16x8 kb00 = *(const u16x8*)kp0, kb01 = *(const u16x8*)(kp0 + 32);
  const u16x8 kb10 = *(const u16x8*)kp1, kb11 = *(const u16x8*)(kp1 + 32);
  const float mvl0 = maskg[b * 2048 + kbase + lq] * LOG2E;
  const float mvl1 = maskg[b * 2048 + kbase + 16 + lq] * LOG2E;
  const float* wbase = winv + bh * 2048;
  const char* Qbase = (const char*)(Qb + (size_t)bh * 2048 * 64);

  const int r0 = tid >> 3;
  const int scol = ((tid & 7) * 16) ^ ((r0 & 7) << 4);
  auto stageQ = [&](int qt, int buf) {
    const char* src = Qbase + (size_t)(qt * 64) * 128;
    char* d = (char*)&Ql[buf][0] + w * 1024;
    gload_lds16(src + (size_t)r0 * 128 + scol, d);
    gload_lds16(src + (size_t)(r0 + 32) * 128 + scol, d + 4096);
  };

  float c0 = 0.f, c1 = 0.f;
  stageQ(q0t, 0);
  stageQ(q0t + 1, 1);
  for (int j = 0; j < 16; ++j) {
    const int qt = q0t + j;
    if (j < 15) vmwait<2>(); else vmwait<0>();
    __builtin_amdgcn_s_barrier();
    const char* Qt = (const char*)&Ql[j % 3][0];
    __builtin_amdgcn_s_setprio(1);
#pragma unroll
    for (int chunk = 0; chunk < 4; ++chunk) {
      const u16x8 qf0 = *(const u16x8*)(Qt + SWZ(chunk * 16 + lq, lg * 16));
      const u16x8 qf1 = *(const u16x8*)(Qt + SWZ(chunk * 16 + lq, 64 + lg * 16));
      f32x4 z = {0.f, 0.f, 0.f, 0.f};
      f32x4 s0 = mfma16(qf0, kb00, z);
      s0 = mfma16(qf1, kb01, s0);
      f32x4 s1 = mfma16(qf0, kb10, z);
      s1 = mfma16(qf1, kb11, s1);
      const f32x4 wv = *(const f32x4*)(wbase + qt * 64 + chunk * 16 + lg * 4);
#pragma unroll
      for (int r = 0; r < 4; ++r) {
        c0 += EXP2(s0[r] + mvl0) * wv[r];
        c1 += EXP2(s1[r] + mvl1) * wv[r];
      }
    }
    __builtin_amdgcn_s_setprio(0);
    __builtin_amdgcn_sched_barrier(0);
    if (j + 2 < 16) stageQ(q0t + j + 2, (j + 2) % 3);
  }
  c0 += __shfl_xor(c0, 16); c0 += __shfl_xor(c0, 32);
  c1 += __shfl_xor(c1, 16); c1 += __shfl_xor(c1, 32);
  if (lg == 0) {
    atomicAdd(&out_cs[b * 2048 + kbase + lq], c0);
    atomicAdd(&out_cs[b * 2048 + kbase + 16 + lq], c1);
  }
}

// ---------- launch ----------
extern "C" void kernel_launch(void* const* d_in, const int* in_sizes, int n_in,
                              void* d_out, int out_size, void* d_ws, size_t ws_size,
                              hipStream_t stream) {
  (void)in_sizes; (void)n_in; (void)out_size; (void)ws_size;
  const float* X    = (const float*)d_in[0];
  const float* mask = (const float*)d_in[1];
  const float* Wq   = (const float*)d_in[2];
  const float* bq   = (const float*)d_in[3];
  const float* Wk   = (const float*)d_in[4];
  const float* bk   = (const float*)d_in[5];
  const float* Wv   = (const float*)d_in[6];
  const float* bv   = (const float*)d_in[7];
  float* out = (float*)d_out;

  char* ws = (char*)d_ws;
  u16* Xb   = (u16*)(ws);
  u16* Wcat = (u16*)(ws + 8388608);
  u16* Qb   = (u16*)(ws + 14680064);
  u16* Kb   = (u16*)(ws + 23068672);
  u16* VTb  = (u16*)(ws + 31457280);
  float* winv = (float*)(ws + 39845888);

  hipMemsetAsync(out + 4194304, 0, 4096 * sizeof(float), stream);

  cast_all<<<7168, 256, 0, stream>>>(X, Wq, Wk, Wv, Xb, Wcat);

  gemm_qkv<<<dim3(24, 32), 256, 0, stream>>>(Xb, Wcat, bq, bk, bv, Qb, Kb, VTb);

  attn_pair<<<512, 512, 0, stream>>>(Qb, Kb, VTb, mask, out, winv);
  colsum_kernel<<<1024, 256, 0, stream>>>(Qb, Kb, mask, winv, out + 4194304);
}

// Round 14
// 139.711 us; speedup vs baseline: 1.2145x; 1.0252x over previous
//
#include <hip/hip_runtime.h>
#include <hip/hip_bf16.h>
#include <stdint.h>

typedef unsigned short u16;
typedef __attribute__((ext_vector_type(8))) unsigned short u16x8;
typedef __attribute__((ext_vector_type(4))) unsigned short u16x4;
typedef __attribute__((ext_vector_type(8))) __bf16 bf16x8;
typedef __attribute__((ext_vector_type(4))) float f32x4;
typedef __attribute__((ext_vector_type(16))) float f32x16;

#define LOG2E 1.44269504088896340736f

#if defined(__has_builtin)
#if __has_builtin(__builtin_amdgcn_exp2f)
#define EXP2(x) __builtin_amdgcn_exp2f(x)
#endif
#endif
#ifndef EXP2
#define EXP2(x) exp2f(x)
#endif

// ---------- helpers ----------
__device__ __forceinline__ f32x4 mfma16(u16x8 a, u16x8 b, f32x4 c) {
  return __builtin_amdgcn_mfma_f32_16x16x32_bf16(
      __builtin_bit_cast(bf16x8, a), __builtin_bit_cast(bf16x8, b), c, 0, 0, 0);
}

__device__ __forceinline__ f32x16 mfma32(u16x8 a, u16x8 b, f32x16 c) {
  return __builtin_amdgcn_mfma_f32_32x32x16_bf16(
      __builtin_bit_cast(bf16x8, a), __builtin_bit_cast(bf16x8, b), c, 0, 0, 0);
}

__device__ __forceinline__ u16 f2bf(float f) {
  unsigned u = __builtin_bit_cast(unsigned, f);
  return (u16)((u + 0x7fffu + ((u >> 16) & 1u)) >> 16);
}

__device__ __forceinline__ unsigned cvtpk(float a, float b) {
  unsigned r;
  asm volatile("v_cvt_pk_bf16_f32 %0, %1, %2" : "=v"(r) : "v"(a), "v"(b));
  return r;
}

// v_permlane32_swap_b32: a[32..63] <-> b[0..31]
__device__ __forceinline__ void pswap(unsigned& a, unsigned& b) {
  asm volatile("v_permlane32_swap_b32 %0, %1" : "+v"(a), "+v"(b));
}

__device__ __forceinline__ void gload_lds16(const void* g, void* l) {
  __builtin_amdgcn_global_load_lds(
      (__attribute__((address_space(1))) void*)const_cast<void*>(g),
      (__attribute__((address_space(3))) void*)l, 16, 0, 0);
}

template<int N> __device__ __forceinline__ void vmwait() {
  __builtin_amdgcn_sched_barrier(0);
  asm volatile("s_waitcnt vmcnt(%0)" :: "n"(N) : "memory");
  __builtin_amdgcn_sched_barrier(0);
}

#define SWZ(row, colbyte) ((((row) * 128) + (colbyte)) ^ (((row) & 7) << 4))

// ---------- merged fp32 -> bf16 casts (X + 3 W's in one launch) ----------
__global__ void cast_all(const float* __restrict__ X,
                         const float* __restrict__ s0, const float* __restrict__ s1,
                         const float* __restrict__ s2,
                         u16* __restrict__ Xb, u16* __restrict__ Wcat) {
  const int bid = blockIdx.x;
  const float* src;
  u16* dst;
  int i;
  if (bid < 4096) {
    src = X; dst = Xb;
    i = bid * 256 + threadIdx.x;
  } else {
    const int wb = bid - 4096;
    const int seg = wb >> 10;
    src = (seg == 0) ? s0 : ((seg == 1) ? s1 : s2);
    dst = Wcat + (size_t)seg * 1048576;
    i = (wb & 1023) * 256 + threadIdx.x;
  }
  f32x4 v = ((const f32x4*)src)[i];
  u16x4 o;
  o[0] = f2bf(v[0]); o[1] = f2bf(v[1]); o[2] = f2bf(v[2]); o[3] = f2bf(v[3]);
  ((u16x4*)dst)[i] = o;
}

// ---------- fused QKV GEMM (3-buf, depth-2, counted vmcnt, swizzled LDS) ----------
__global__ __launch_bounds__(256) void gemm_qkv(
    const u16* __restrict__ A, const u16* __restrict__ Bm,
    const float* __restrict__ bq, const float* __restrict__ bk, const float* __restrict__ bv,
    u16* __restrict__ Qb, u16* __restrict__ Kb, u16* __restrict__ VTb) {
  __shared__ __align__(16) u16 Asm[3][4096];
  __shared__ __align__(16) u16 Bsm[3][4096];
  const int tid = threadIdx.x;
  const int wave = tid >> 6, lane = tid & 63;
  const int lq = lane & 15, lg = lane >> 4;
  const int wr = wave >> 1, wc = wave & 1;
  const int lin = blockIdx.y * 24 + blockIdx.x;
  const int wg = (lin & 7) * 96 + (lin >> 3);
  const int m0 = (wg / 24) * 128, n0 = (wg % 24) * 128;

  f32x4 zero = {0.f, 0.f, 0.f, 0.f};
  f32x4 acc[4][4];
#pragma unroll
  for (int mi = 0; mi < 4; ++mi)
#pragma unroll
    for (int ni = 0; ni < 4; ++ni) acc[mi][ni] = zero;

  // staging chunk -> logical (row, 16B-k-unit), inverse of the read swizzle
  int rA0, k16A0, rA1, k16A1;
  {
    const int cc0 = wave * 128 + lane;
    const int ln0 = cc0 >> 3, sp0 = (cc0 & 7) ^ (ln0 & 7);
    rA0 = ln0 * 2 + (sp0 >> 2); k16A0 = sp0 & 3;
    const int cc1 = cc0 + 64;
    const int ln1 = cc1 >> 3, sp1 = (cc1 & 7) ^ (ln1 & 7);
    rA1 = ln1 * 2 + (sp1 >> 2); k16A1 = sp1 & 3;
  }

  auto stage = [&](int kt, int buf) {
    const int kk = kt * 32;
    gload_lds16(A + (size_t)(m0 + rA0) * 1024 + kk + k16A0 * 8,
                (char*)&Asm[buf][0] + (wave * 2 + 0) * 1024);
    gload_lds16(A + (size_t)(m0 + rA1) * 1024 + kk + k16A1 * 8,
                (char*)&Asm[buf][0] + (wave * 2 + 1) * 1024);
    gload_lds16(Bm + (size_t)(n0 + rA0) * 1024 + kk + k16A0 * 8,
                (char*)&Bsm[buf][0] + (wave * 2 + 0) * 1024);
    gload_lds16(Bm + (size_t)(n0 + rA1) * 1024 + kk + k16A1 * 8,
                (char*)&Bsm[buf][0] + (wave * 2 + 1) * 1024);
  };

  stage(0, 0);
  stage(1, 1);
  for (int kt = 0; kt < 32; ++kt) {
    if (kt < 31) vmwait<4>(); else vmwait<0>();
    __builtin_amdgcn_s_barrier();
    if (kt + 2 < 32) stage(kt + 2, (kt + 2) % 3);
    const int cur = kt % 3;

    __builtin_amdgcn_s_setprio(1);
    u16x8 af[4], bfr[4];
#pragma unroll
    for (int mi = 0; mi < 4; ++mi) {
      const int rA = wr * 64 + mi * 16 + lq;
      const int lnA = rA >> 1;
      const int spA = ((rA & 1) << 2) | lg;
      af[mi] = *(const u16x8*)((const char*)&Asm[cur][0] +
                               lnA * 128 + ((spA ^ (lnA & 7)) << 4));
    }
#pragma unroll
    for (int ni = 0; ni < 4; ++ni) {
      const int rB = wc * 64 + ni * 16 + lq;
      const int lnB = rB >> 1;
      const int spB = ((rB & 1) << 2) | lg;
      bfr[ni] = *(const u16x8*)((const char*)&Bsm[cur][0] +
                                lnB * 128 + ((spB ^ (lnB & 7)) << 4));
    }
#pragma unroll
    for (int mi = 0; mi < 4; ++mi)
#pragma unroll
      for (int ni = 0; ni < 4; ++ni)
        acc[mi][ni] = mfma16(af[mi], bfr[ni], acc[mi][ni]);
    __builtin_amdgcn_s_setprio(0);
  }

  const int which = n0 >> 10;
  const float* bias = (which == 0) ? bq : ((which == 1) ? bk : bv);
  const float scl = (which == 0) ? (0.125f * LOG2E) : 1.0f;
#pragma unroll
  for (int mi = 0; mi < 4; ++mi) {
    const int m = m0 + wr * 64 + mi * 16 + lg * 4;
    const int bb = m >> 11;
    const int s = m & 2047;
#pragma unroll
    for (int ni = 0; ni < 4; ++ni) {
      const int n = n0 + wc * 64 + ni * 16 + lq;
      const int d = n & 1023;
      const int h = d >> 6, dh = d & 63;
      const float bi = bias[d];
#pragma unroll
      for (int r = 0; r < 4; ++r) {
        float v = (acc[mi][ni][r] + bi) * scl;
        if (which == 2)
          VTb[(((size_t)bb * 16 + h) * 64 + dh) * 2048 + (size_t)(s + r)] = f2bf(v);
        else {
          u16* dst = (which == 0) ? Qb : Kb;
          dst[(((size_t)bb * 16 + h) * 2048 + (size_t)(s + r)) * 64 + dh] = f2bf(v);
        }
      }
    }
  }
}

// ---------- attention: pair-split, 32x32 MFMA, K-tile 32, 4-buf depth-3 ----------
// 512 thr = 8 waves: hf=w>>2 (k-half), p=w&3 (q-subtile of 32). Grid 512 ->
// 2 blocks/CU, 16 waves/CU. Depth-3 prefetch (vmwait<4>); LDS pair merge.
__global__ __launch_bounds__(512) void attn_pair(
    const u16* __restrict__ Qb, const u16* __restrict__ Kb, const u16* __restrict__ VTb,
    const float* __restrict__ maskg, float* __restrict__ out_ctx, float* __restrict__ winv) {
  // smem: K[hf][buf0..3] @ hf*16384+buf*4096 (32KB), VT @ 32768+... (32KB) = 64KB
  __shared__ __align__(16) char smem[65536];

  const int tid = threadIdx.x;
  const int w = tid >> 6, lane = tid & 63;
  const int l31 = lane & 31, h = lane >> 5;
  const int hf = w >> 2, p = w & 3;
  const int bid = (blockIdx.x & 7) * 64 + (blockIdx.x >> 3);
  const int qt = bid & 15, bh = bid >> 4;
  const int b = bh >> 4, hh = bh & 15;
  const int qw = qt * 128 + p * 32;

  // Q frags: lane holds Q[qw+l31][dh = 16dq + 8h + j]
  const u16* qp = Qb + ((size_t)bh * 2048 + qw + l31) * 64 + h * 8;
  u16x8 qa[4];
#pragma unroll
  for (int dq = 0; dq < 4; ++dq) qa[dq] = *(const u16x8*)(qp + dq * 16);

  const char* KbaseG = (const char*)(Kb + (size_t)bh * 2048 * 64);
  const char* VTbaseG = (const char*)(VTb + (size_t)bh * 64 * 2048);
  const float* mbase = maskg + b * 2048;

  // staging (per half: 256 threads, 1 K-chunk + 1 VT-chunk each)
  const int t8 = tid & 255;
  const int srowK = t8 >> 3;
  const int scolK = ((t8 & 7) * 16) ^ ((srowK & 7) << 4);
  const int lineV = t8 >> 3;
  const int spV = (t8 & 7) ^ (lineV & 7);
  const int dhV = lineV * 2 + (spV >> 2);
  const int kbV = (spV & 3) * 16;

  auto stage = [&](int kt, int buf) {   // 2 loads/thread
    char* kd = smem + hf * 16384 + buf * 4096 + (w & 3) * 1024;
    gload_lds16(KbaseG + (size_t)(kt * 32 + srowK) * 128 + scolK, kd);
    char* vd = smem + 32768 + hf * 16384 + buf * 4096 + (w & 3) * 1024;
    gload_lds16(VTbaseG + (size_t)dhV * 4096 + (size_t)kt * 64 + kbV, vd);
  };

  f32x16 accpv[2];
#pragma unroll
  for (int db = 0; db < 2; ++db)
#pragma unroll
    for (int r = 0; r < 16; ++r) accpv[db][r] = 0.f;
  float l_l = 0.f;

  const int kt0 = hf * 32;
  stage(kt0, 0);
  stage(kt0 + 1, 1);
  stage(kt0 + 2, 2);
  for (int j = 0; j < 32; ++j) {
    const int kt = kt0 + j;
    if (j < 30) vmwait<4>(); else if (j == 30) vmwait<2>(); else vmwait<0>();
    __builtin_amdgcn_s_barrier();
    const char* Kt = smem + hf * 16384 + (j & 3) * 4096;
    const char* Vt = smem + 32768 + hf * 16384 + (j & 3) * 4096;

    __builtin_amdgcn_s_setprio(1);
    // QK^T: S[k = kt*32 + (r&3)+8(r>>2)+4h][q = l31]
    f32x16 s;
#pragma unroll
    for (int r = 0; r < 16; ++r) s[r] = 0.f;
#pragma unroll
    for (int dq = 0; dq < 4; ++dq) {
      const u16x8 ka = *(const u16x8*)(Kt + SWZ(l31, dq * 32 + h * 16));
      s = mfma32(ka, qa[dq], s);
    }
    float pv[16];
#pragma unroll
    for (int g = 0; g < 4; ++g) {
      const f32x4 mv = *(const f32x4*)(mbase + kt * 32 + g * 8 + h * 4);
#pragma unroll
      for (int j2 = 0; j2 < 4; ++j2)
        pv[g * 4 + j2] = EXP2(fmaf(mv[j2], LOG2E, s[g * 4 + j2]));
    }
    l_l += ((pv[0] + pv[1]) + (pv[2] + pv[3])) + ((pv[4] + pv[5]) + (pv[6] + pv[7])) +
           ((pv[8] + pv[9]) + (pv[10] + pv[11])) + ((pv[12] + pv[13]) + (pv[14] + pv[15]));
    // P -> PV A-frags: pairs packed, lane-halves swapped
    unsigned a01 = cvtpk(pv[0], pv[1]), a23 = cvtpk(pv[2], pv[3]);
    unsigned a45 = cvtpk(pv[4], pv[5]), a67 = cvtpk(pv[6], pv[7]);
    unsigned b01 = cvtpk(pv[8], pv[9]), b23 = cvtpk(pv[10], pv[11]);
    unsigned b45 = cvtpk(pv[12], pv[13]), b67 = cvtpk(pv[14], pv[15]);
    pswap(a01, a45); pswap(a23, a67);  // frag ks2=0: k = kt*32 + [0,16)
    pswap(b01, b45); pswap(b23, b67);  // frag ks2=1: k = kt*32 + [16,32)
    uint4 f1 = {a01, a23, a45, a67};
    uint4 f2 = {b01, b23, b45, b67};
    u16x8 pf[2] = {__builtin_bit_cast(u16x8, f1), __builtin_bit_cast(u16x8, f2)};
    // PV: ctx[q][dh] += P[q][k] * VT[dh][k]  (pair-line swizzled VT reads)
#pragma unroll
    for (int ks2 = 0; ks2 < 2; ++ks2) {
#pragma unroll
      for (int db = 0; db < 2; ++db) {
        const int rowV = db * 32 + l31;
        const int lnV = rowV >> 1;
        const int sV = ((rowV & 1) << 2) | (ks2 << 1) | h;
        const u16x8 vt = *(const u16x8*)(Vt + lnV * 128 + ((sV ^ (lnV & 7)) << 4));
        accpv[db] = mfma32(pf[ks2], vt, accpv[db]);
      }
    }
    __builtin_amdgcn_s_setprio(0);
    __builtin_amdgcn_sched_barrier(0);
    if (j + 3 < 32) stage(kt0 + j + 3, (j + 3) & 3);
  }

  // merge the two lane-halves of l (distinct k each)
  l_l += __shfl_xor(l_l, 32);

  // ---- pair merge through LDS (staging buffers dead) ----
  __syncthreads();
  float* pairctx = (float*)smem;              // 4 p x 32q x 64dh = 32 KB
  float* pairl = (float*)(smem + 32768);      // 4 p x 32
  if (hf == 1) {
#pragma unroll
    for (int db = 0; db < 2; ++db)
#pragma unroll
      for (int r = 0; r < 16; ++r) {
        const int q = (r & 3) + (r >> 2) * 8 + h * 4;
        pairctx[p * 2048 + q * 64 + db * 32 + l31] = accpv[db][r];
      }
    if (h == 0) pairl[p * 32 + l31] = l_l;
  }
  __syncthreads();
  if (hf == 0) {
    const float lt = l_l + pairl[p * 32 + l31];
    const float il = 1.0f / lt;
    if (h == 0) winv[bh * 2048 + qw + l31] = il;
#pragma unroll
    for (int r = 0; r < 16; ++r) {
      const int q = (r & 3) + (r >> 2) * 8 + h * 4;
      const float ilr = __shfl(il, q);
      const size_t row = (size_t)(b * 2048 + qw + q) * 1024 + hh * 64;
      out_ctx[row + l31] = (accpv[0][r] + pairctx[p * 2048 + q * 64 + l31]) * ilr;
      out_ctx[row + 32 + l31] = (accpv[1][r] + pairctx[p * 2048 + q * 64 + 32 + l31]) * ilr;
    }
  }
}

// ---------- colsum: c_k = sum_q exp2(s + mask*L) * winv_q ----------
// 256 thr = 4 waves; wave owns 64 k (4 reg K-frag groups); block = 256 k x 512 q.
// Grid 1024 = 32 bh x 8 ktile x 4 qq -> 4 blocks/CU, 16 waves/CU.
__global__ __launch_bounds__(256) void colsum_kernel(
    const u16* __restrict__ Qb, const u16* __restrict__ Kb,
    const float* __restrict__ maskg, const float* __restrict__ winv,
    float* __restrict__ out_cs) {
  __shared__ __align__(16) u16 Ql[3][4096];

  const int tid = threadIdx.x;
  const int w = tid >> 6, lane = tid & 63;
  const int lq = lane & 15, lg = lane >> 4;
  const int bid = (blockIdx.x & 7) * 128 + (blockIdx.x >> 3);
  const int ktile = bid & 7, qq = (bid >> 3) & 3, bh = bid >> 5;
  const int b = bh >> 4;
  const int kbase = ktile * 256 + w * 64;
  const int q0t = qq * 8;   // this block's 8 Q-tiles (512 q)

  // four reg-resident K fragment groups: k = kbase + g*16 + lq
  const u16* kp = Kb + ((size_t)bh * 2048 + kbase + lq) * 64 + lg * 8;
  u16x8 kf[4][2];
  float mvl[4];
#pragma unroll
  for (int g = 0; g < 4; ++g) {
    kf[g][0] = *(const u16x8*)(kp + (size_t)g * 16 * 64);
    kf[g][1] = *(const u16x8*)(kp + (size_t)g * 16 * 64 + 32);
    mvl[g] = maskg[b * 2048 + kbase + g * 16 + lq] * LOG2E;
  }
  const float* wbase = winv + bh * 2048;
  const char* Qbase = (const char*)(Qb + (size_t)bh * 2048 * 64);

  const int r0 = tid >> 3;
  const int scol = ((tid & 7) * 16) ^ ((r0 & 7) << 4);
  auto stageQ = [&](int qt, int buf) {   // 2 loads/thread
    const char* src = Qbase + (size_t)(qt * 64) * 128;
    char* d = (char*)&Ql[buf][0] + w * 1024;
    gload_lds16(src + (size_t)r0 * 128 + scol, d);
    gload_lds16(src + (size_t)(r0 + 32) * 128 + scol, d + 4096);
  };

  float c0 = 0.f, c1 = 0.f, c2 = 0.f, c3 = 0.f;
  stageQ(q0t, 0);
  stageQ(q0t + 1, 1);
  for (int j = 0; j < 8; ++j) {
    const int qt = q0t + j;
    if (j < 7) vmwait<2>(); else vmwait<0>();
    __builtin_amdgcn_s_barrier();
    const char* Qt = (const char*)&Ql[j % 3][0];
    __builtin_amdgcn_s_setprio(1);
#pragma unroll
    for (int chunk = 0; chunk < 4; ++chunk) {
      const u16x8 qf0 = *(const u16x8*)(Qt + SWZ(chunk * 16 + lq, lg * 16));
      const u16x8 qf1 = *(const u16x8*)(Qt + SWZ(chunk * 16 + lq, 64 + lg * 16));
      const f32x4 wv = *(const f32x4*)(wbase + qt * 64 + chunk * 16 + lg * 4);
      f32x4 z = {0.f, 0.f, 0.f, 0.f};
      f32x4 s0 = mfma16(qf0, kf[0][0], z); s0 = mfma16(qf1, kf[0][1], s0);
      f32x4 s1 = mfma16(qf0, kf[1][0], z); s1 = mfma16(qf1, kf[1][1], s1);
      f32x4 s2 = mfma16(qf0, kf[2][0], z); s2 = mfma16(qf1, kf[2][1], s2);
      f32x4 s3 = mfma16(qf0, kf[3][0], z); s3 = mfma16(qf1, kf[3][1], s3);
#pragma unroll
      for (int r = 0; r < 4; ++r) {
        c0 += EXP2(s0[r] + mvl[0]) * wv[r];
        c1 += EXP2(s1[r] + mvl[1]) * wv[r];
        c2 += EXP2(s2[r] + mvl[2]) * wv[r];
        c3 += EXP2(s3[r] + mvl[3]) * wv[r];
      }
    }
    __builtin_amdgcn_s_setprio(0);
    __builtin_amdgcn_sched_barrier(0);
    if (j + 2 < 8) stageQ(q0t + j + 2, (j + 2) % 3);
  }
  c0 += __shfl_xor(c0, 16); c0 += __shfl_xor(c0, 32);
  c1 += __shfl_xor(c1, 16); c1 += __shfl_xor(c1, 32);
  c2 += __shfl_xor(c2, 16); c2 += __shfl_xor(c2, 32);
  c3 += __shfl_xor(c3, 16); c3 += __shfl_xor(c3, 32);
  if (lg == 0) {
    atomicAdd(&out_cs[b * 2048 + kbase + lq], c0);
    atomicAdd(&out_cs[b * 2048 + kbase + 16 + lq], c1);
    atomicAdd(&out_cs[b * 2048 + kbase + 32 + lq], c2);
    atomicAdd(&out_cs[b * 2048 + kbase + 48 + lq], c3);
  }
}

// ---------- launch ----------
extern "C" void kernel_launch(void* const* d_in, const int* in_sizes, int n_in,
                              void* d_out, int out_size, void* d_ws, size_t ws_size,
                              hipStream_t stream) {
  (void)in_sizes; (void)n_in; (void)out_size; (void)ws_size;
  const float* X    = (const float*)d_in[0];
  const float* mask = (const float*)d_in[1];
  const float* Wq   = (const float*)d_in[2];
  const float* bq   = (const float*)d_in[3];
  const float* Wk   = (const float*)d_in[4];
  const float* bk   = (const float*)d_in[5];
  const float* Wv   = (const float*)d_in[6];
  const float* bv   = (const float*)d_in[7];
  float* out = (float*)d_out;

  char* ws = (char*)d_ws;
  u16* Xb   = (u16*)(ws);
  u16* Wcat = (u16*)(ws + 8388608);
  u16* Qb   = (u16*)(ws + 14680064);
  u16* Kb   = (u16*)(ws + 23068672);
  u16* VTb  = (u16*)(ws + 31457280);
  float* winv = (float*)(ws + 39845888);

  hipMemsetAsync(out + 4194304, 0, 4096 * sizeof(float), stream);

  cast_all<<<7168, 256, 0, stream>>>(X, Wq, Wk, Wv, Xb, Wcat);

  gemm_qkv<<<dim3(24, 32), 256, 0, stream>>>(Xb, Wcat, bq, bk, bv, Qb, Kb, VTb);

  attn_pair<<<512, 512, 0, stream>>>(Qb, Kb, VTb, mask, out, winv);
  colsum_kernel<<<1024, 256, 0, stream>>>(Qb, Kb, mask, winv, out + 4194304);
}

// Round 15
// 127.307 us; speedup vs baseline: 1.3328x; 1.0974x over previous
//
#include <hip/hip_runtime.h>
#include <hip/hip_bf16.h>
#include <stdint.h>

typedef unsigned short u16;
typedef __attribute__((ext_vector_type(8))) unsigned short u16x8;
typedef __attribute__((ext_vector_type(4))) unsigned short u16x4;
typedef __attribute__((ext_vector_type(8))) __bf16 bf16x8;
typedef __attribute__((ext_vector_type(4))) float f32x4;
typedef __attribute__((ext_vector_type(16))) float f32x16;

#define LOG2E 1.44269504088896340736f

#if defined(__has_builtin)
#if __has_builtin(__builtin_amdgcn_exp2f)
#define EXP2(x) __builtin_amdgcn_exp2f(x)
#endif
#endif
#ifndef EXP2
#define EXP2(x) exp2f(x)
#endif

// ---------- helpers ----------
__device__ __forceinline__ f32x4 mfma16(u16x8 a, u16x8 b, f32x4 c) {
  return __builtin_amdgcn_mfma_f32_16x16x32_bf16(
      __builtin_bit_cast(bf16x8, a), __builtin_bit_cast(bf16x8, b), c, 0, 0, 0);
}

__device__ __forceinline__ f32x16 mfma32(u16x8 a, u16x8 b, f32x16 c) {
  return __builtin_amdgcn_mfma_f32_32x32x16_bf16(
      __builtin_bit_cast(bf16x8, a), __builtin_bit_cast(bf16x8, b), c, 0, 0, 0);
}

__device__ __forceinline__ u16 f2bf(float f) {
  unsigned u = __builtin_bit_cast(unsigned, f);
  return (u16)((u + 0x7fffu + ((u >> 16) & 1u)) >> 16);
}

__device__ __forceinline__ unsigned cvtpk(float a, float b) {
  unsigned r;
  asm volatile("v_cvt_pk_bf16_f32 %0, %1, %2" : "=v"(r) : "v"(a), "v"(b));
  return r;
}

// v_permlane32_swap_b32: a[32..63] <-> b[0..31]
__device__ __forceinline__ void pswap(unsigned& a, unsigned& b) {
  asm volatile("v_permlane32_swap_b32 %0, %1" : "+v"(a), "+v"(b));
}

__device__ __forceinline__ void gload_lds16(const void* g, void* l) {
  __builtin_amdgcn_global_load_lds(
      (__attribute__((address_space(1))) void*)const_cast<void*>(g),
      (__attribute__((address_space(3))) void*)l, 16, 0, 0);
}

template<int N> __device__ __forceinline__ void vmwait() {
  __builtin_amdgcn_sched_barrier(0);
  asm volatile("s_waitcnt vmcnt(%0)" :: "n"(N) : "memory");
  __builtin_amdgcn_sched_barrier(0);
}

#define SWZ(row, colbyte) ((((row) * 128) + (colbyte)) ^ (((row) & 7) << 4))

// ---------- merged casts: X + 3 W's -> bf16, maskL = mask*log2e, zero out_cs ----
__global__ void cast_all(const float* __restrict__ X,
                         const float* __restrict__ s0, const float* __restrict__ s1,
                         const float* __restrict__ s2, const float* __restrict__ mask,
                         u16* __restrict__ Xb, u16* __restrict__ Wcat,
                         float* __restrict__ maskL, float* __restrict__ out_cs) {
  const int bid = blockIdx.x;
  if (bid >= 7168) {  // mask*log2e + colsum zero: 4096 floats each
    const int i = (bid - 7168) * 256 + threadIdx.x;  // < 1024 f32x4 units
    f32x4 m = ((const f32x4*)mask)[i];
    m[0] *= LOG2E; m[1] *= LOG2E; m[2] *= LOG2E; m[3] *= LOG2E;
    ((f32x4*)maskL)[i] = m;
    f32x4 z = {0.f, 0.f, 0.f, 0.f};
    ((f32x4*)out_cs)[i] = z;
    return;
  }
  const float* src;
  u16* dst;
  int i;
  if (bid < 4096) {
    src = X; dst = Xb;
    i = bid * 256 + threadIdx.x;
  } else {
    const int wb = bid - 4096;
    const int seg = wb >> 10;
    src = (seg == 0) ? s0 : ((seg == 1) ? s1 : s2);
    dst = Wcat + (size_t)seg * 1048576;
    i = (wb & 1023) * 256 + threadIdx.x;
  }
  f32x4 v = ((const f32x4*)src)[i];
  u16x4 o;
  o[0] = f2bf(v[0]); o[1] = f2bf(v[1]); o[2] = f2bf(v[2]); o[3] = f2bf(v[3]);
  ((u16x4*)dst)[i] = o;
}

// ---------- fused QKV GEMM (3-buf, depth-2, counted vmcnt, swizzled LDS) ----------
__global__ __launch_bounds__(256) void gemm_qkv(
    const u16* __restrict__ A, const u16* __restrict__ Bm,
    const float* __restrict__ bq, const float* __restrict__ bk, const float* __restrict__ bv,
    u16* __restrict__ Qb, u16* __restrict__ Kb, u16* __restrict__ VTb) {
  __shared__ __align__(16) u16 Asm[3][4096];
  __shared__ __align__(16) u16 Bsm[3][4096];
  const int tid = threadIdx.x;
  const int wave = tid >> 6, lane = tid & 63;
  const int lq = lane & 15, lg = lane >> 4;
  const int wr = wave >> 1, wc = wave & 1;
  const int lin = blockIdx.y * 24 + blockIdx.x;
  const int wg = (lin & 7) * 96 + (lin >> 3);
  const int m0 = (wg / 24) * 128, n0 = (wg % 24) * 128;

  f32x4 zero = {0.f, 0.f, 0.f, 0.f};
  f32x4 acc[4][4];
#pragma unroll
  for (int mi = 0; mi < 4; ++mi)
#pragma unroll
    for (int ni = 0; ni < 4; ++ni) acc[mi][ni] = zero;

  int rA0, k16A0, rA1, k16A1;
  {
    const int cc0 = wave * 128 + lane;
    const int ln0 = cc0 >> 3, sp0 = (cc0 & 7) ^ (ln0 & 7);
    rA0 = ln0 * 2 + (sp0 >> 2); k16A0 = sp0 & 3;
    const int cc1 = cc0 + 64;
    const int ln1 = cc1 >> 3, sp1 = (cc1 & 7) ^ (ln1 & 7);
    rA1 = ln1 * 2 + (sp1 >> 2); k16A1 = sp1 & 3;
  }

  auto stage = [&](int kt, int buf) {
    const int kk = kt * 32;
    gload_lds16(A + (size_t)(m0 + rA0) * 1024 + kk + k16A0 * 8,
                (char*)&Asm[buf][0] + (wave * 2 + 0) * 1024);
    gload_lds16(A + (size_t)(m0 + rA1) * 1024 + kk + k16A1 * 8,
                (char*)&Asm[buf][0] + (wave * 2 + 1) * 1024);
    gload_lds16(Bm + (size_t)(n0 + rA0) * 1024 + kk + k16A0 * 8,
                (char*)&Bsm[buf][0] + (wave * 2 + 0) * 1024);
    gload_lds16(Bm + (size_t)(n0 + rA1) * 1024 + kk + k16A1 * 8,
                (char*)&Bsm[buf][0] + (wave * 2 + 1) * 1024);
  };

  stage(0, 0);
  stage(1, 1);
  for (int kt = 0; kt < 32; ++kt) {
    if (kt < 31) vmwait<4>(); else vmwait<0>();
    __builtin_amdgcn_s_barrier();
    if (kt + 2 < 32) stage(kt + 2, (kt + 2) % 3);
    const int cur = kt % 3;

    __builtin_amdgcn_s_setprio(1);
    u16x8 af[4], bfr[4];
#pragma unroll
    for (int mi = 0; mi < 4; ++mi) {
      const int rA = wr * 64 + mi * 16 + lq;
      const int lnA = rA >> 1;
      const int spA = ((rA & 1) << 2) | lg;
      af[mi] = *(const u16x8*)((const char*)&Asm[cur][0] +
                               lnA * 128 + ((spA ^ (lnA & 7)) << 4));
    }
#pragma unroll
    for (int ni = 0; ni < 4; ++ni) {
      const int rB = wc * 64 + ni * 16 + lq;
      const int lnB = rB >> 1;
      const int spB = ((rB & 1) << 2) | lg;
      bfr[ni] = *(const u16x8*)((const char*)&Bsm[cur][0] +
                                lnB * 128 + ((spB ^ (lnB & 7)) << 4));
    }
#pragma unroll
    for (int mi = 0; mi < 4; ++mi)
#pragma unroll
      for (int ni = 0; ni < 4; ++ni)
        acc[mi][ni] = mfma16(af[mi], bfr[ni], acc[mi][ni]);
    __builtin_amdgcn_s_setprio(0);
  }

  const int which = n0 >> 10;
  const float* bias = (which == 0) ? bq : ((which == 1) ? bk : bv);
  const float scl = (which == 0) ? (0.125f * LOG2E) : 1.0f;
#pragma unroll
  for (int mi = 0; mi < 4; ++mi) {
    const int m = m0 + wr * 64 + mi * 16 + lg * 4;
    const int bb = m >> 11;
    const int s = m & 2047;
#pragma unroll
    for (int ni = 0; ni < 4; ++ni) {
      const int n = n0 + wc * 64 + ni * 16 + lq;
      const int d = n & 1023;
      const int h = d >> 6, dh = d & 63;
      const float bi = bias[d];
#pragma unroll
      for (int r = 0; r < 4; ++r) {
        float v = (acc[mi][ni][r] + bi) * scl;
        if (which == 2)
          VTb[(((size_t)bb * 16 + h) * 64 + dh) * 2048 + (size_t)(s + r)] = f2bf(v);
        else {
          u16* dst = (which == 0) ? Qb : Kb;
          dst[(((size_t)bb * 16 + h) * 2048 + (size_t)(s + r)) * 64 + dh] = f2bf(v);
        }
      }
    }
  }
}

// ---------- attention: pair-split, 32x32 MFMA, mask-in-C via LDS, pure vm FIFO --
// 512 thr = 8 waves: hf=w>>2 (k-half), p=w&3 (q-subtile of 32). Grid 512 ->
// 2 blocks/CU, 16 waves/CU. 3-buf depth-2 (vmwait<2>); compute phase VMEM-free.
__global__ __launch_bounds__(512) void attn_pair(
    const u16* __restrict__ Qb, const u16* __restrict__ Kb, const u16* __restrict__ VTb,
    const float* __restrict__ maskL, float* __restrict__ out_ctx, float* __restrict__ winv) {
  // K[hf][buf] @ hf*12288+buf*4096 (24KB), VT @ 24576+..., maskLds @ 49152 (8KB)
  __shared__ __align__(16) char smem[57344];

  const int tid = threadIdx.x;
  const int w = tid >> 6, lane = tid & 63;
  const int l31 = lane & 31, h = lane >> 5;
  const int hf = w >> 2, p = w & 3;
  const int bid = (blockIdx.x & 7) * 64 + (blockIdx.x >> 3);
  const int qt = bid & 15, bh = bid >> 4;
  const int b = bh >> 4, hh = bh & 15;
  const int qw = qt * 128 + p * 32;

  // stage maskL (2048 floats for this b) into LDS once
  float* maskLds = (float*)(smem + 49152);
  {
    const f32x4 m = ((const f32x4*)(maskL + b * 2048))[tid];
    *(f32x4*)(maskLds + tid * 4) = m;
  }

  // Q frags: lane holds Q[qw+l31][dh = 16dq + 8h + j]
  const u16* qp = Qb + ((size_t)bh * 2048 + qw + l31) * 64 + h * 8;
  u16x8 qa[4];
#pragma unroll
  for (int dq = 0; dq < 4; ++dq) qa[dq] = *(const u16x8*)(qp + dq * 16);

  const char* KbaseG = (const char*)(Kb + (size_t)bh * 2048 * 64);
  const char* VTbaseG = (const char*)(VTb + (size_t)bh * 64 * 2048);

  const int t8 = tid & 255;
  const int srowK = t8 >> 3;
  const int scolK = ((t8 & 7) * 16) ^ ((srowK & 7) << 4);
  const int lineV = t8 >> 3;
  const int spV = (t8 & 7) ^ (lineV & 7);
  const int dhV = lineV * 2 + (spV >> 2);
  const int kbV = (spV & 3) * 16;

  auto stage = [&](int kt, int buf) {   // 2 loads/thread
    char* kd = smem + hf * 12288 + buf * 4096 + (w & 3) * 1024;
    gload_lds16(KbaseG + (size_t)(kt * 32 + srowK) * 128 + scolK, kd);
    char* vd = smem + 24576 + hf * 12288 + buf * 4096 + (w & 3) * 1024;
    gload_lds16(VTbaseG + (size_t)dhV * 4096 + (size_t)kt * 64 + kbV, vd);
  };

  f32x16 accpv[2];
#pragma unroll
  for (int db = 0; db < 2; ++db)
#pragma unroll
    for (int r = 0; r < 16; ++r) accpv[db][r] = 0.f;
  float l_l = 0.f;

  __syncthreads();  // maskLds visible before loop (drains vm too; prologue only)
  const int kt0 = hf * 32;
  stage(kt0, 0);
  stage(kt0 + 1, 1);
  for (int j = 0; j < 32; ++j) {
    const int kt = kt0 + j;
    if (j < 31) vmwait<2>(); else vmwait<0>();
    __builtin_amdgcn_s_barrier();
    const char* Kt = smem + hf * 12288 + (j % 3) * 4096;
    const char* Vt = smem + 24576 + hf * 12288 + (j % 3) * 4096;

    __builtin_amdgcn_s_setprio(1);
    // C-init = maskL values (per k row) -> exp2(s) needs no fmaf
    f32x16 s;
    {
      const float* mrow = maskLds + kt * 32 + h * 4;
#pragma unroll
      for (int g = 0; g < 4; ++g) {
        const f32x4 mv = *(const f32x4*)(mrow + g * 8);
        s[g * 4 + 0] = mv[0]; s[g * 4 + 1] = mv[1];
        s[g * 4 + 2] = mv[2]; s[g * 4 + 3] = mv[3];
      }
    }
    // QK^T: S[k = kt*32 + (r&3)+8(r>>2)+4h][q = l31]
#pragma unroll
    for (int dq = 0; dq < 4; ++dq) {
      const u16x8 ka = *(const u16x8*)(Kt + SWZ(l31, dq * 32 + h * 16));
      s = mfma32(ka, qa[dq], s);
    }
    float pv[16];
#pragma unroll
    for (int r = 0; r < 16; ++r) pv[r] = EXP2(s[r]);
    l_l += ((pv[0] + pv[1]) + (pv[2] + pv[3])) + ((pv[4] + pv[5]) + (pv[6] + pv[7])) +
           ((pv[8] + pv[9]) + (pv[10] + pv[11])) + ((pv[12] + pv[13]) + (pv[14] + pv[15]));
    // P -> PV A-frags: pairs packed, lane-halves swapped
    unsigned a01 = cvtpk(pv[0], pv[1]), a23 = cvtpk(pv[2], pv[3]);
    unsigned a45 = cvtpk(pv[4], pv[5]), a67 = cvtpk(pv[6], pv[7]);
    unsigned b01 = cvtpk(pv[8], pv[9]), b23 = cvtpk(pv[10], pv[11]);
    unsigned b45 = cvtpk(pv[12], pv[13]), b67 = cvtpk(pv[14], pv[15]);
    pswap(a01, a45); pswap(a23, a67);  // frag ks2=0: k = kt*32 + [0,16)
    pswap(b01, b45); pswap(b23, b67);  // frag ks2=1: k = kt*32 + [16,32)
    uint4 f1 = {a01, a23, a45, a67};
    uint4 f2 = {b01, b23, b45, b67};
    u16x8 pf[2] = {__builtin_bit_cast(u16x8, f1), __builtin_bit_cast(u16x8, f2)};
    // PV: ctx[q][dh] += P[q][k] * VT[dh][k]  (pair-line swizzled VT reads)
#pragma unroll
    for (int ks2 = 0; ks2 < 2; ++ks2) {
#pragma unroll
      for (int db = 0; db < 2; ++db) {
        const int rowV = db * 32 + l31;
        const int lnV = rowV >> 1;
        const int sV = ((rowV & 1) << 2) | (ks2 << 1) | h;
        const u16x8 vt = *(const u16x8*)(Vt + lnV * 128 + ((sV ^ (lnV & 7)) << 4));
        accpv[db] = mfma32(pf[ks2], vt, accpv[db]);
      }
    }
    __builtin_amdgcn_s_setprio(0);
    __builtin_amdgcn_sched_barrier(0);
    if (j + 2 < 32) stage(kt0 + j + 2, (j + 2) % 3);
  }

  // merge the two lane-halves of l (distinct k each)
  l_l += __shfl_xor(l_l, 32);

  // ---- pair merge through LDS (staging buffers dead) ----
  __syncthreads();
  float* pairctx = (float*)smem;              // 4 p x 32q x 64dh = 32 KB
  float* pairl = (float*)(smem + 32768);      // 4 p x 32 (dead VT region)
  if (hf == 1) {
#pragma unroll
    for (int db = 0; db < 2; ++db)
#pragma unroll
      for (int r = 0; r < 16; ++r) {
        const int q = (r & 3) + (r >> 2) * 8 + h * 4;
        pairctx[p * 2048 + q * 64 + db * 32 + l31] = accpv[db][r];
      }
    if (h == 0) pairl[p * 32 + l31] = l_l;
  }
  __syncthreads();
  if (hf == 0) {
    const float lt = l_l + pairl[p * 32 + l31];
    const float il = 1.0f / lt;
    if (h == 0) winv[bh * 2048 + qw + l31] = il;
#pragma unroll
    for (int r = 0; r < 16; ++r) {
      const int q = (r & 3) + (r >> 2) * 8 + h * 4;
      const float ilr = __shfl(il, q);
      const size_t row = (size_t)(b * 2048 + qw + q) * 1024 + hh * 64;
      out_ctx[row + l31] = (accpv[0][r] + pairctx[p * 2048 + q * 64 + l31]) * ilr;
      out_ctx[row + 32 + l31] = (accpv[1][r] + pairctx[p * 2048 + q * 64 + 32 + l31]) * ilr;
    }
  }
}

// ---------- colsum: c_k = sum_q exp2(s + maskL) * winv_q ----------
// 256 thr = 4 waves; wave owns 64 k (4 reg K-frag groups, mask folded into C);
// winv chunk in LDS; block = 256 k x 512 q. Grid 1024 -> 4 blocks/CU.
__global__ __launch_bounds__(256) void colsum_kernel(
    const u16* __restrict__ Qb, const u16* __restrict__ Kb,
    const float* __restrict__ maskL, const float* __restrict__ winv,
    float* __restrict__ out_cs) {
  __shared__ __align__(16) u16 Ql[3][4096];
  __shared__ float winvLds[512];

  const int tid = threadIdx.x;
  const int w = tid >> 6, lane = tid & 63;
  const int lq = lane & 15, lg = lane >> 4;
  const int bid = (blockIdx.x & 7) * 128 + (blockIdx.x >> 3);
  const int ktile = bid & 7, qq = (bid >> 3) & 3, bh = bid >> 5;
  const int b = bh >> 4;
  const int kbase = ktile * 256 + w * 64;
  const int q0t = qq * 8;   // this block's 8 Q-tiles (512 q)

  // winv chunk -> LDS (512 floats)
  if (tid < 128) {
    const f32x4 v = ((const f32x4*)(winv + (size_t)bh * 2048 + q0t * 64))[tid];
    *(f32x4*)(winvLds + tid * 4) = v;
  }

  // four reg-resident K fragment groups; mask folded into loop-invariant C vecs
  const u16* kp = Kb + ((size_t)bh * 2048 + kbase + lq) * 64 + lg * 8;
  u16x8 kf[4][2];
  f32x4 zg[4];
#pragma unroll
  for (int g = 0; g < 4; ++g) {
    kf[g][0] = *(const u16x8*)(kp + (size_t)g * 16 * 64);
    kf[g][1] = *(const u16x8*)(kp + (size_t)g * 16 * 64 + 32);
    const float m = maskL[b * 2048 + kbase + g * 16 + lq];
    zg[g][0] = m; zg[g][1] = m; zg[g][2] = m; zg[g][3] = m;
  }
  const char* Qbase = (const char*)(Qb + (size_t)bh * 2048 * 64);

  const int r0 = tid >> 3;
  const int scol = ((tid & 7) * 16) ^ ((r0 & 7) << 4);
  auto stageQ = [&](int qt, int buf) {   // 2 loads/thread
    const char* src = Qbase + (size_t)(qt * 64) * 128;
    char* d = (char*)&Ql[buf][0] + w * 1024;
    gload_lds16(src + (size_t)r0 * 128 + scol, d);
    gload_lds16(src + (size_t)(r0 + 32) * 128 + scol, d + 4096);
  };

  float c0 = 0.f, c1 = 0.f, c2 = 0.f, c3 = 0.f;
  __syncthreads();  // winvLds visible (prologue-only full drain)
  stageQ(q0t, 0);
  stageQ(q0t + 1, 1);
  for (int j = 0; j < 8; ++j) {
    if (j < 7) vmwait<2>(); else vmwait<0>();
    __builtin_amdgcn_s_barrier();
    const char* Qt = (const char*)&Ql[j % 3][0];
    __builtin_amdgcn_s_setprio(1);
#pragma unroll
    for (int chunk = 0; chunk < 4; ++chunk) {
      const u16x8 qf0 = *(const u16x8*)(Qt + SWZ(chunk * 16 + lq, lg * 16));
      const u16x8 qf1 = *(const u16x8*)(Qt + SWZ(chunk * 16 + lq, 64 + lg * 16));
      const f32x4 wv = *(const f32x4*)(winvLds + j * 64 + chunk * 16 + lg * 4);
      f32x4 s0 = mfma16(qf0, kf[0][0], zg[0]); s0 = mfma16(qf1, kf[0][1], s0);
      f32x4 s1 = mfma16(qf0, kf[1][0], zg[1]); s1 = mfma16(qf1, kf[1][1], s1);
      f32x4 s2 = mfma16(qf0, kf[2][0], zg[2]); s2 = mfma16(qf1, kf[2][1], s2);
      f32x4 s3 = mfma16(qf0, kf[3][0], zg[3]); s3 = mfma16(qf1, kf[3][1], s3);
#pragma unroll
      for (int r = 0; r < 4; ++r) {
        c0 = fmaf(EXP2(s0[r]), wv[r], c0);
        c1 = fmaf(EXP2(s1[r]), wv[r], c1);
        c2 = fmaf(EXP2(s2[r]), wv[r], c2);
        c3 = fmaf(EXP2(s3[r]), wv[r], c3);
      }
    }
    __builtin_amdgcn_s_setprio(0);
    __builtin_amdgcn_sched_barrier(0);
    if (j + 2 < 8) stageQ(q0t + j + 2, (j + 2) % 3);
  }
  c0 += __shfl_xor(c0, 16); c0 += __shfl_xor(c0, 32);
  c1 += __shfl_xor(c1, 16); c1 += __shfl_xor(c1, 32);
  c2 += __shfl_xor(c2, 16); c2 += __shfl_xor(c2, 32);
  c3 += __shfl_xor(c3, 16); c3 += __shfl_xor(c3, 32);
  if (lg == 0) {
    atomicAdd(&out_cs[b * 2048 + kbase + lq], c0);
    atomicAdd(&out_cs[b * 2048 + kbase + 16 + lq], c1);
    atomicAdd(&out_cs[b * 2048 + kbase + 32 + lq], c2);
    atomicAdd(&out_cs[b * 2048 + kbase + 48 + lq], c3);
  }
}

// ---------- launch ----------
extern "C" void kernel_launch(void* const* d_in, const int* in_sizes, int n_in,
                              void* d_out, int out_size, void* d_ws, size_t ws_size,
                              hipStream_t stream) {
  (void)in_sizes; (void)n_in; (void)out_size; (void)ws_size;
  const float* X    = (const float*)d_in[0];
  const float* mask = (const float*)d_in[1];
  const float* Wq   = (const float*)d_in[2];
  const float* bq   = (const float*)d_in[3];
  const float* Wk   = (const float*)d_in[4];
  const float* bk   = (const float*)d_in[5];
  const float* Wv   = (const float*)d_in[6];
  const float* bv   = (const float*)d_in[7];
  float* out = (float*)d_out;

  char* ws = (char*)d_ws;
  u16* Xb   = (u16*)(ws);
  u16* Wcat = (u16*)(ws + 8388608);
  u16* Qb   = (u16*)(ws + 14680064);
  u16* Kb   = (u16*)(ws + 23068672);
  u16* VTb  = (u16*)(ws + 31457280);
  float* winv  = (float*)(ws + 39845888);   // 256 KiB
  float* maskL = (float*)(ws + 40108032);   // 16 KiB

  cast_all<<<7172, 256, 0, stream>>>(X, Wq, Wk, Wv, mask, Xb, Wcat,
                                     maskL, out + 4194304);

  gemm_qkv<<<dim3(24, 32), 256, 0, stream>>>(Xb, Wcat, bq, bk, bv, Qb, Kb, VTb);

  attn_pair<<<512, 512, 0, stream>>>(Qb, Kb, VTb, maskL, out, winv);
  colsum_kernel<<<1024, 256, 0, stream>>>(Qb, Kb, maskL, winv, out + 4194304);
}